// Round 10
// baseline (1502.679 us; speedup 1.0000x reference)
//
#include <hip/hip_runtime.h>
#include <hip/hip_bf16.h>

#define N_NODES 100000
#define N_EDGES 1600000

using bf16 = __hip_bfloat16;
typedef unsigned int u32;

static __device__ __forceinline__ float b2f(bf16 v){ return __bfloat162float(v); }

// float loader: f32m=1 -> buffer is float32, f32m=0 -> buffer is bf16
static __device__ __forceinline__ float ldf(const void* p, long i, int f32m){
  return f32m ? ((const float*)p)[i] : b2f(((const bf16*)p)[i]);
}

static __device__ __forceinline__ u32 f2bf_rne(float f){
  u32 b = __float_as_uint(f);
  return (b + 0x7fffu + ((b>>16)&1u)) >> 16;
}

static __device__ __forceinline__ float pick8(const float* t, int m){
  float a0=(m&1)?t[1]:t[0], a1=(m&1)?t[3]:t[2], a2=(m&1)?t[5]:t[4], a3=(m&1)?t[7]:t[6];
  float b0=(m&2)?a1:a0, b1=(m&2)?a3:a2;
  return (m&4)?b1:b0;
}

// ---------------- dtype detection (device-side, deterministic) ----------------
__global__ void k_detect(const u32* __restrict__ xw, const int* __restrict__ eiw,
                         int* __restrict__ flags){
  __shared__ int s_wild, s_nzodd;
  if(threadIdx.x==0){ s_wild=0; s_nzodd=0; }
  __syncthreads();
  int wild=0, nz=0;
  for(int k=threadIdx.x;k<2048;k+=256){
    u32 w  = xw[k];
    u32 lo = w & 0xffffu;
    int e  = (int)((lo>>7)&0xffu);
    if((lo & 0x7fffu)!=0u && (e<90 || e>160)) wild++;
    if(eiw[2*k+1]!=0) nz++;
  }
  atomicAdd(&s_wild, wild);
  atomicAdd(&s_nzodd, nz);
  __syncthreads();
  if(threadIdx.x==0){
    flags[0] = (s_wild > 512) ? 1 : 0;   // 1: floats are f32
    flags[1] = (s_nzodd == 0) ? 1 : 0;   // 1: indices are int64
  }
}

__global__ void k_zero2(int* __restrict__ a, int* __restrict__ b){
  int i = blockIdx.x*256 + threadIdx.x;
  if(i<N_NODES){ a[i]=0; b[i]=0; }
}

// ---------------- CSR build ----------------

__global__ void k_count(const int* __restrict__ ei, const int* __restrict__ flags,
                        int* __restrict__ deg){
  int e = blockIdx.x*256 + threadIdx.x;
  int i64 = flags[1];
  if(e < N_EDGES){
    long di = i64 ? 2l*(N_EDGES + e) : (long)(N_EDGES + e);
    atomicAdd(&deg[ei[di]], 1);
  }
}

__global__ void k_scan(const int* __restrict__ deg, int* __restrict__ off){
  __shared__ int sums[1024];
  __shared__ int base[1025];
  int t = threadIdx.x;
  const int chunk = (N_NODES + 1023)/1024;
  int b0 = t*chunk, b1 = min(b0+chunk, N_NODES);
  int s = 0;
  for(int i=b0;i<b1;i++) s += deg[i];
  sums[t] = s;
  __syncthreads();
  if(t==0){
    int acc=0;
    for(int i=0;i<1024;i++){ base[i]=acc; acc+=sums[i]; }
    base[1024]=acc;
  }
  __syncthreads();
  int acc = base[t];
  for(int i=b0;i<b1;i++){ off[i]=acc; acc+=deg[i]; }
  if(t==0) off[N_NODES] = base[1024];
}

__global__ void k_fill(const int* __restrict__ ei, const void* __restrict__ ew,
                       const int* __restrict__ flags, const int* __restrict__ off,
                       int* __restrict__ cur, int* __restrict__ csr_src,
                       float* __restrict__ csr_ew){
  int e = blockIdx.x*256 + threadIdx.x;
  int i64 = flags[1], f32m = flags[0];
  if(e < N_EDGES){
    int s = ei[i64 ? 2l*e : (long)e];
    int d = ei[i64 ? 2l*(N_EDGES+e) : (long)(N_EDGES+e)];
    int p = atomicAdd(&cur[d], 1);
    int idx = off[d] + p;
    csr_src[idx] = s;
    csr_ew[idx]  = ldf(ew, e, f32m);
  }
}

// ---------------- weight pre-pack: out[c*64+k] = {bf16(Wr), bf16(Wl)} ----------------

__global__ void k_pack(const void* __restrict__ Wl, const void* __restrict__ Wr,
                       const int* __restrict__ flags, int CIN, int COUT,
                       u32* __restrict__ out){
  int i = blockIdx.x*256 + threadIdx.x;
  if(i < CIN*64){
    int c = i>>6, k = i&63;
    u32 v = 0;
    if(k < COUT){
      int f32m = flags[0];
      u32 l = f2bf_rne(ldf(Wl,(long)c*COUT+k,f32m));
      u32 r = f2bf_rne(ldf(Wr,(long)c*COUT+k,f32m));
      v = (r<<16) | l;
    }
    out[i] = v;
  }
}

// ---------------- embedding: tiled LDS GEMM, 64 nodes/block, 4x5 reg tile ----------------
// output: bf16, stride 128, channels 80..127 zero-padded

__global__ __launch_bounds__(256,2) void k_embed(const void* __restrict__ x,
                                                 const void* __restrict__ W,
                                                 const void* __restrict__ b,
                                                 const int* __restrict__ flags,
                                                 bf16* __restrict__ h){
  __shared__ float xs[100][65];     // [channel][node], pad 65 -> conflict-free
  __shared__ float Ws[100*80];
  const int t = threadIdx.x;
  const int n0 = blockIdx.x*64;
  const int f32m = flags[0];
  for(int i=t;i<8000;i+=256) Ws[i]=ldf(W,i,f32m);
  for(int idx=t; idx<6400; idx+=256){
    int n = idx/100, c = idx - n*100;
    float v = (n0+n < N_NODES) ? ldf(x,(long)(n0+n)*100+c,f32m) : 0.f;
    xs[c][n] = v;
  }
  __syncthreads();

  const int ng = t&15, og = t>>4;    // nodes ng*4..+3, outs og*5..+4
  float acc[4][5];
  #pragma unroll
  for(int j=0;j<5;j++){
    float bj = ldf(b, og*5+j, f32m);
    #pragma unroll
    for(int i=0;i<4;i++) acc[i][j] = bj;
  }
  #pragma unroll 2
  for(int c=0;c<100;c++){
    float xv[4];
    #pragma unroll
    for(int i=0;i<4;i++) xv[i] = xs[c][ng*4+i];
    #pragma unroll
    for(int j=0;j<5;j++){
      float wj = Ws[c*80+og*5+j];
      #pragma unroll
      for(int i=0;i<4;i++) acc[i][j] = fmaf(xv[i], wj, acc[i][j]);
    }
  }
  #pragma unroll
  for(int i=0;i<4;i++){
    int n = n0 + ng*4 + i;
    if(n < N_NODES){
      #pragma unroll
      for(int j=0;j<5;j++) h[(long)n*128 + og*5+j] = __float2bfloat16(fmaxf(acc[i][j], 0.f));
    }
  }
  // zero the pad channels 80..127
  for(int idx=t; idx<64*48; idx+=256){
    int n = idx/48, c = 80 + (idx - 48*(idx/48));
    if(n0+n < N_NODES) h[(long)(n0+n)*128 + c] = __float2bfloat16(0.f);
  }
}

// ---------------- fused SAGE layer (bf16 rows, uint4 gather) ----------------
// one wave per node. h rows are packed bf16, stride BROW (128 for layer0 in,
// 64 otherwise). LPE=BROW/8 lanes read a row as uint4 (8 ch each); EPW=64/LPE
// edges per wave load; 2 loads in flight. xor-reduce across edge groups,
// shfl-redistribute to lane=channel, matvec with packed bf16 weight pairs,
// L2 normalize, relu, store bf16 (or final out).

template<int CIN, int COUT, int BROW, bool LAST>
__global__ __launch_bounds__(256,4) void k_sage(
    const u32* __restrict__ hin, const int* __restrict__ off,
    const int* __restrict__ csr_src, const float* __restrict__ csr_ew,
    const u32* __restrict__ Wp, const void* __restrict__ bias,
    const int* __restrict__ flags, bf16* __restrict__ hout, void* __restrict__ outp)
{
  const int f32m = flags[0];
  const int lane = threadIdx.x&63;
  const int node = blockIdx.x*4 + (threadIdx.x>>6);   // grid covers N_NODES exactly
  constexpr int NC  = (CIN+63)/64;                    // 1 (64ch) or 2 (80ch)
  constexpr int LPE = BROW/8;                         // lanes per row: 8 or 16
  constexpr int EPW = 64/LPE;                         // edges per wave load: 8 or 4
  constexpr int LSH = (LPE==16)?4:3;

  const int sub = lane>>LSH;                          // edge slot (all lanes active)
  const int cl  = lane & (LPE-1);                     // uint4 index within row

  // self row -> f32 regs (lane = channel)
  float hreg[NC];
  const u32* hr = hin + (long)node*(BROW/2);
  { u32 uv = hr[lane>>1];
    hreg[0] = __uint_as_float((lane&1)? (uv&0xffff0000u) : (uv<<16)); }
  if(NC==2){
    u32 uv = hr[32+(lane>>1)];
    float v = __uint_as_float((lane&1)? (uv&0xffff0000u) : (uv<<16));
    hreg[1] = (lane<16) ? v : 0.f;
  }

  float a[8];
  #pragma unroll
  for(int k=0;k<8;k++) a[k]=0.f;

  const uint4* hin4 = (const uint4*)hin;
  const int e0 = off[node], e1 = off[node+1];
  for(int base=e0; base<e1; base+=64){
    const int cnt = min(64, e1-base);
    int   sv = (lane<cnt) ? csr_src[base+lane] : 0;
    float wv = LAST ? 1.f : ((lane<cnt) ? csr_ew[base+lane] : 0.f);
    for(int j=0; j<cnt; j+=2*EPW){
      int ei0 = j + sub, ei1 = j + EPW + sub;
      bool v0 = ei0 < cnt, v1 = ei1 < cnt;
      int x0 = v0 ? ei0 : 0, x1 = v1 ? ei1 : 0;
      int   s0 = __shfl(sv, x0),  s1 = __shfl(sv, x1);
      float w0 = __shfl(wv, x0) * (v0 ? 1.f : 0.f);
      float w1 = __shfl(wv, x1) * (v1 ? 1.f : 0.f);
      uint4 r0 = hin4[(long)s0*LPE + cl];
      uint4 r1 = hin4[(long)s1*LPE + cl];
      a[0]=fmaf(w0,__uint_as_float(r0.x<<16),a[0]); a[1]=fmaf(w0,__uint_as_float(r0.x&0xffff0000u),a[1]);
      a[2]=fmaf(w0,__uint_as_float(r0.y<<16),a[2]); a[3]=fmaf(w0,__uint_as_float(r0.y&0xffff0000u),a[3]);
      a[4]=fmaf(w0,__uint_as_float(r0.z<<16),a[4]); a[5]=fmaf(w0,__uint_as_float(r0.z&0xffff0000u),a[5]);
      a[6]=fmaf(w0,__uint_as_float(r0.w<<16),a[6]); a[7]=fmaf(w0,__uint_as_float(r0.w&0xffff0000u),a[7]);
      a[0]=fmaf(w1,__uint_as_float(r1.x<<16),a[0]); a[1]=fmaf(w1,__uint_as_float(r1.x&0xffff0000u),a[1]);
      a[2]=fmaf(w1,__uint_as_float(r1.y<<16),a[2]); a[3]=fmaf(w1,__uint_as_float(r1.y&0xffff0000u),a[3]);
      a[4]=fmaf(w1,__uint_as_float(r1.z<<16),a[4]); a[5]=fmaf(w1,__uint_as_float(r1.z&0xffff0000u),a[5]);
      a[6]=fmaf(w1,__uint_as_float(r1.w<<16),a[6]); a[7]=fmaf(w1,__uint_as_float(r1.w&0xffff0000u),a[7]);
    }
  }

  // xor-reduce across edge groups: every lane ends with full sums for its cl
  #pragma unroll
  for(int k=0;k<8;k++){
    if(LPE==8) a[k] += __shfl_xor(a[k], 8);
    a[k] += __shfl_xor(a[k], 16);
    a[k] += __shfl_xor(a[k], 32);
  }
  // lane q (q<LPE) holds channels 8q..8q+7 in a[0..7]

  const float inv = 1.f/fmaxf((float)(e1-e0), 1.f);
  float aggv[NC];
  {
    int q = lane>>3, m = lane&7;          // ch lane -> src lane (lane>>3) < 8 <= LPE
    float t0[8];
    #pragma unroll
    for(int k=0;k<8;k++) t0[k] = __shfl(a[k], q);
    aggv[0] = pick8(t0, m) * inv;
    if(NC==2){                            // ch 64+lane (lane<16) -> src lane 8+(lane>>3)
      int q2 = 8 + (lane>>3);
      float t1[8];
      #pragma unroll
      for(int k=0;k<8;k++) t1[k] = __shfl(a[k], q2);
      aggv[1] = (lane<16) ? pick8(t1, m) * inv : 0.f;
    }
  }

  // matvec: o[lane] = bias[lane] + sum_c agg[c]*Wl[c][lane] + h[c]*Wr[c][lane]
  float o = (lane<COUT) ? ldf(bias,lane,f32m) : 0.f;
  #pragma unroll
  for(int c=0;c<CIN;c++){
    float ag = __shfl(aggv[c>>6], c&63);
    float hv = __shfl(hreg[c>>6], c&63);
    u32 p = Wp[(c<<6)|lane];               // zero-padded to 64 lanes, no OOB
    o = fmaf(ag, __uint_as_float(p<<16), o);
    o = fmaf(hv, __uint_as_float(p & 0xffff0000u), o);
  }

  float sq = o*o;                          // lanes >= COUT contribute 0
  #pragma unroll
  for(int d=1; d<64; d<<=1) sq += __shfl_xor(sq, d);
  float r = o * (1.f/fmaxf(sqrtf(sq), 1e-12f));
  if(!LAST) r = fmaxf(r, 0.f);

  if(LAST){
    if(lane<COUT){
      long oi = (long)node*COUT+lane;
      if(f32m) ((float*)outp)[oi] = r;
      else     ((bf16*)outp)[oi]  = __float2bfloat16(r);
    }
  } else {
    hout[(long)node*64 + lane] = __float2bfloat16(r);   // COUT==64
  }
}

// ---------------- launch ----------------

extern "C" void kernel_launch(void* const* d_in, const int* in_sizes, int n_in,
                              void* d_out, int out_size, void* d_ws, size_t ws_size,
                              hipStream_t stream){
  const void* x    = d_in[0];
  const int*  ei   = (const int*)d_in[1];
  const void* ew   = d_in[2];
  const void* embW = d_in[3];
  const void* embB = d_in[4];
  const void *Wl0=d_in[5],  *Wr0=d_in[6],  *b0=d_in[7];
  const void *Wl1=d_in[8],  *Wr1=d_in[9],  *b1=d_in[10];
  const void *Wl2=d_in[11], *Wr2=d_in[12], *b2=d_in[13];
  const void *Wl3=d_in[14], *Wr3=d_in[15], *b3=d_in[16];
  const void *Wlo=d_in[17], *Wro=d_in[18], *bo=d_in[19];

  // 256B-aligned workspace carves (uint4 gather targets must be 16B-aligned)
  char* w = (char*)d_ws;
  auto carve = [&](size_t nbytes)->char*{
    char* r = w; w += (nbytes + 255) & ~(size_t)255; return r;
  };
  int*   flags   = (int*)carve(16);
  int*   deg     = (int*)carve((size_t)N_NODES*4);
  int*   cur     = (int*)carve((size_t)N_NODES*4);
  int*   off     = (int*)carve((size_t)(N_NODES+1)*4);
  int*   csr_src = (int*)carve((size_t)N_EDGES*4);
  float* csr_ew  = (float*)carve((size_t)N_EDGES*4);
  u32*   Wp0     = (u32*)carve((size_t)80*64*4);
  u32*   Wp1     = (u32*)carve((size_t)64*64*4);
  u32*   Wp2     = (u32*)carve((size_t)64*64*4);
  u32*   Wp3     = (u32*)carve((size_t)64*64*4);
  u32*   Wpo     = (u32*)carve((size_t)64*64*4);
  bf16*  hA      = (bf16*)carve((size_t)N_NODES*128*2);  // stride 128 (layer0 in), reused stride 64 later
  bf16*  hB      = (bf16*)carve((size_t)N_NODES*64*2);   // stride 64

  k_detect<<<1, 256, 0, stream>>>((const u32*)x, ei, flags);
  k_zero2<<<(N_NODES+255)/256, 256, 0, stream>>>(deg, cur);
  k_count<<<N_EDGES/256, 256, 0, stream>>>(ei, flags, deg);
  k_scan <<<1, 1024, 0, stream>>>(deg, off);
  k_fill <<<N_EDGES/256, 256, 0, stream>>>(ei, ew, flags, off, cur, csr_src, csr_ew);

  k_pack<<<20, 256, 0, stream>>>(Wl0, Wr0, flags, 80, 64, Wp0);
  k_pack<<<16, 256, 0, stream>>>(Wl1, Wr1, flags, 64, 64, Wp1);
  k_pack<<<16, 256, 0, stream>>>(Wl2, Wr2, flags, 64, 64, Wp2);
  k_pack<<<16, 256, 0, stream>>>(Wl3, Wr3, flags, 64, 64, Wp3);
  k_pack<<<16, 256, 0, stream>>>(Wlo, Wro, flags, 64, 18, Wpo);

  k_embed<<<(N_NODES+63)/64, 256, 0, stream>>>(x, embW, embB, flags, hA);

  k_sage<80,64,128,false><<<N_NODES/4, 256, 0, stream>>>((const u32*)hA, off, csr_src, csr_ew, Wp0, b0, flags, hB, nullptr);
  k_sage<64,64,64,false ><<<N_NODES/4, 256, 0, stream>>>((const u32*)hB, off, csr_src, csr_ew, Wp1, b1, flags, hA, nullptr);
  k_sage<64,64,64,false ><<<N_NODES/4, 256, 0, stream>>>((const u32*)hA, off, csr_src, csr_ew, Wp2, b2, flags, hB, nullptr);
  k_sage<64,64,64,false ><<<N_NODES/4, 256, 0, stream>>>((const u32*)hB, off, csr_src, csr_ew, Wp3, b3, flags, hA, nullptr);
  k_sage<64,18,64,true  ><<<N_NODES/4, 256, 0, stream>>>((const u32*)hA, off, csr_src, csr_ew, Wpo, bo, flags, nullptr, d_out);
}

// Round 11
// 963.761 us; speedup vs baseline: 1.5592x; 1.5592x over previous
//
#include <hip/hip_runtime.h>
#include <hip/hip_bf16.h>

#define N_NODES 100000
#define N_EDGES 1600000

using bf16 = __hip_bfloat16;
typedef unsigned int u32;

static __device__ __forceinline__ float b2f(bf16 v){ return __bfloat162float(v); }

// float loader: f32m=1 -> buffer is float32, f32m=0 -> buffer is bf16
static __device__ __forceinline__ float ldf(const void* p, long i, int f32m){
  return f32m ? ((const float*)p)[i] : b2f(((const bf16*)p)[i]);
}

static __device__ __forceinline__ u32 f2bf_rne(float f){
  u32 b = __float_as_uint(f);
  return (b + 0x7fffu + ((b>>16)&1u)) >> 16;
}

// ---------------- dtype detection (device-side, deterministic) ----------------
__global__ void k_detect(const u32* __restrict__ xw, const int* __restrict__ eiw,
                         int* __restrict__ flags){
  __shared__ int s_wild, s_nzodd;
  if(threadIdx.x==0){ s_wild=0; s_nzodd=0; }
  __syncthreads();
  int wild=0, nz=0;
  for(int k=threadIdx.x;k<2048;k+=256){
    u32 w  = xw[k];
    u32 lo = w & 0xffffu;
    int e  = (int)((lo>>7)&0xffu);
    if((lo & 0x7fffu)!=0u && (e<90 || e>160)) wild++;
    if(eiw[2*k+1]!=0) nz++;
  }
  atomicAdd(&s_wild, wild);
  atomicAdd(&s_nzodd, nz);
  __syncthreads();
  if(threadIdx.x==0){
    flags[0] = (s_wild > 512) ? 1 : 0;   // 1: floats are f32
    flags[1] = (s_nzodd == 0) ? 1 : 0;   // 1: indices are int64
  }
}

__global__ void k_zero2(int* __restrict__ a, int* __restrict__ b){
  int i = blockIdx.x*256 + threadIdx.x;
  if(i<N_NODES){ a[i]=0; b[i]=0; }
}

// ---------------- CSR build ----------------

__global__ void k_count(const int* __restrict__ ei, const int* __restrict__ flags,
                        int* __restrict__ deg){
  int e = blockIdx.x*256 + threadIdx.x;
  int i64 = flags[1];
  if(e < N_EDGES){
    long di = i64 ? 2l*(N_EDGES + e) : (long)(N_EDGES + e);
    atomicAdd(&deg[ei[di]], 1);
  }
}

__global__ void k_scan(const int* __restrict__ deg, int* __restrict__ off){
  __shared__ int sums[1024];
  __shared__ int base[1025];
  int t = threadIdx.x;
  const int chunk = (N_NODES + 1023)/1024;
  int b0 = t*chunk, b1 = min(b0+chunk, N_NODES);
  int s = 0;
  for(int i=b0;i<b1;i++) s += deg[i];
  sums[t] = s;
  __syncthreads();
  if(t==0){
    int acc=0;
    for(int i=0;i<1024;i++){ base[i]=acc; acc+=sums[i]; }
    base[1024]=acc;
  }
  __syncthreads();
  int acc = base[t];
  for(int i=b0;i<b1;i++){ off[i]=acc; acc+=deg[i]; }
  if(t==0) off[N_NODES] = base[1024];
}

__global__ void k_fill(const int* __restrict__ ei, const void* __restrict__ ew,
                       const int* __restrict__ flags, const int* __restrict__ off,
                       int* __restrict__ cur, int* __restrict__ csr_src,
                       float* __restrict__ csr_ew){
  int e = blockIdx.x*256 + threadIdx.x;
  int i64 = flags[1], f32m = flags[0];
  if(e < N_EDGES){
    int s = ei[i64 ? 2l*e : (long)e];
    int d = ei[i64 ? 2l*(N_EDGES+e) : (long)(N_EDGES+e)];
    int p = atomicAdd(&cur[d], 1);
    int idx = off[d] + p;
    csr_src[idx] = s;
    csr_ew[idx]  = ldf(ew, e, f32m);
  }
}

// ---------------- weight pre-pack: out[c*64+k] = {bf16(Wr), bf16(Wl)} ----------------

__global__ void k_pack(const void* __restrict__ Wl, const void* __restrict__ Wr,
                       const int* __restrict__ flags, int CIN, int COUT,
                       u32* __restrict__ out){
  int i = blockIdx.x*256 + threadIdx.x;
  if(i < CIN*64){
    int c = i>>6, k = i&63;
    u32 v = 0;
    if(k < COUT){
      int f32m = flags[0];
      u32 l = f2bf_rne(ldf(Wl,(long)c*COUT+k,f32m));
      u32 r = f2bf_rne(ldf(Wr,(long)c*COUT+k,f32m));
      v = (r<<16) | l;
    }
    out[i] = v;
  }
}

// ---------------- embedding: tiled LDS GEMM, 64 nodes/block, 4x5 reg tile ----------------

__global__ __launch_bounds__(256,2) void k_embed(const void* __restrict__ x,
                                                 const void* __restrict__ W,
                                                 const void* __restrict__ b,
                                                 const int* __restrict__ flags,
                                                 float* __restrict__ h){
  __shared__ float xs[100][65];     // [channel][node], pad 65 -> conflict-free
  __shared__ float Ws[100*80];
  const int t = threadIdx.x;
  const int n0 = blockIdx.x*64;
  const int f32m = flags[0];
  for(int i=t;i<8000;i+=256) Ws[i]=ldf(W,i,f32m);
  for(int idx=t; idx<6400; idx+=256){
    int n = idx/100, c = idx - n*100;
    float v = (n0+n < N_NODES) ? ldf(x,(long)(n0+n)*100+c,f32m) : 0.f;
    xs[c][n] = v;
  }
  __syncthreads();

  const int ng = t&15, og = t>>4;    // nodes ng*4..+3, outs og*5..+4
  float acc[4][5];
  #pragma unroll
  for(int j=0;j<5;j++){
    float bj = ldf(b, og*5+j, f32m);
    #pragma unroll
    for(int i=0;i<4;i++) acc[i][j] = bj;
  }
  #pragma unroll 2
  for(int c=0;c<100;c++){
    float xv[4];
    #pragma unroll
    for(int i=0;i<4;i++) xv[i] = xs[c][ng*4+i];
    #pragma unroll
    for(int j=0;j<5;j++){
      float wj = Ws[c*80+og*5+j];
      #pragma unroll
      for(int i=0;i<4;i++) acc[i][j] = fmaf(xv[i], wj, acc[i][j]);
    }
  }
  #pragma unroll
  for(int i=0;i<4;i++){
    int n = n0 + ng*4 + i;
    if(n < N_NODES){
      #pragma unroll
      for(int j=0;j<5;j++) h[(long)n*80 + og*5+j] = fmaxf(acc[i][j], 0.f);
    }
  }
}

// ---------------- fused SAGE layer (f32 rows, float4 gather, 4-deep ILP) ----------------
// one wave per node. Gather: CIN/4 lanes per edge read the neighbor row as
// float4; 4 independent row loads in flight. xor/3-way reduce across edge
// groups -> lane q<LPE holds channels 4q..4q+3. Matvec reads that layout
// directly via compile-time readlane broadcasts; self row comes from scalar
// (wave-uniform) loads. Packed bf16 weight pairs from global (L1-resident).
// L2 normalize, relu, store. hin/hout 16B-aligned (ws carves 256B-aligned).

template<int CIN, int COUT, bool LAST>
__global__ __launch_bounds__(256,4) void k_sage(
    const float* __restrict__ hin, const int* __restrict__ off,
    const int* __restrict__ csr_src, const float* __restrict__ csr_ew,
    const u32* __restrict__ Wp, const void* __restrict__ bias,
    const int* __restrict__ flags, float* __restrict__ hout, void* __restrict__ outp)
{
  const int f32m = flags[0];
  const int lane = threadIdx.x&63;
  const int node = blockIdx.x*4 + (threadIdx.x>>6);   // grid covers N_NODES exactly
  constexpr int LPE = CIN/4;                          // lanes per edge-row: 16 or 20
  constexpr int EPW = 64/LPE;                         // edges per wave load: 4 or 3

  const int sub = lane/LPE;                           // edge slot
  const int cl  = lane - sub*LPE;                     // float4-quad within row
  const bool lact = (sub < EPW);

  float ax=0.f, ay=0.f, az=0.f, aw=0.f;
  const int e0 = off[node], e1 = off[node+1];
  for(int base=e0; base<e1; base+=64){
    const int cnt = min(64, e1-base);
    int   sv = (lane<cnt) ? csr_src[base+lane] : 0;
    float wv = LAST ? 1.f : ((lane<cnt) ? csr_ew[base+lane] : 0.f);
    for(int j=0; j<cnt; j+=4*EPW){
      int ei0 = j+sub, ei1 = j+EPW+sub, ei2 = j+2*EPW+sub, ei3 = j+3*EPW+sub;
      bool v0 = lact && (ei0<cnt), v1 = lact && (ei1<cnt);
      bool v2 = lact && (ei2<cnt), v3 = lact && (ei3<cnt);
      int x0 = v0?ei0:0, x1 = v1?ei1:0, x2 = v2?ei2:0, x3 = v3?ei3:0;
      int   s0=__shfl(sv,x0), s1=__shfl(sv,x1), s2=__shfl(sv,x2), s3=__shfl(sv,x3);
      float w0=__shfl(wv,x0)*(v0?1.f:0.f), w1=__shfl(wv,x1)*(v1?1.f:0.f);
      float w2=__shfl(wv,x2)*(v2?1.f:0.f), w3=__shfl(wv,x3)*(v3?1.f:0.f);
      const float4 r0 = *(const float4*)(hin + (long)s0*CIN + 4*cl);
      const float4 r1 = *(const float4*)(hin + (long)s1*CIN + 4*cl);
      const float4 r2 = *(const float4*)(hin + (long)s2*CIN + 4*cl);
      const float4 r3 = *(const float4*)(hin + (long)s3*CIN + 4*cl);
      ax = fmaf(w0,r0.x, fmaf(w1,r1.x, fmaf(w2,r2.x, fmaf(w3,r3.x, ax))));
      ay = fmaf(w0,r0.y, fmaf(w1,r1.y, fmaf(w2,r2.y, fmaf(w3,r3.y, ay))));
      az = fmaf(w0,r0.z, fmaf(w1,r1.z, fmaf(w2,r2.z, fmaf(w3,r3.z, az))));
      aw = fmaf(w0,r0.w, fmaf(w1,r1.w, fmaf(w2,r2.w, fmaf(w3,r3.w, aw))));
    }
  }

  // reduce across edge groups: lane q<LPE ends with full sums for quad q
  if(EPW == 4){
    ax += __shfl_xor(ax,16); ax += __shfl_xor(ax,32);
    ay += __shfl_xor(ay,16); ay += __shfl_xor(ay,32);
    az += __shfl_xor(az,16); az += __shfl_xor(az,32);
    aw += __shfl_xor(aw,16); aw += __shfl_xor(aw,32);
  } else {                       // EPW==3: groups at lanes 0..19 / 20..39 / 40..59
    ax = __shfl(ax,cl) + __shfl(ax,cl+20) + __shfl(ax,cl+40);
    ay = __shfl(ay,cl) + __shfl(ay,cl+20) + __shfl(ay,cl+40);
    az = __shfl(az,cl) + __shfl(az,cl+20) + __shfl(az,cl+40);
    aw = __shfl(aw,cl) + __shfl(aw,cl+20) + __shfl(aw,cl+40);
  }
  const float inv = 1.f/fmaxf((float)(e1-e0), 1.f);
  ax *= inv; ay *= inv; az *= inv; aw *= inv;

  // self row via wave-uniform scalar loads
  const float* hs = hin + (long)__builtin_amdgcn_readfirstlane(node)*CIN;

  // matvec: o[lane] = bias[lane] + sum_c agg[c]*Wl[c][lane] + h[c]*Wr[c][lane]
  // agg[c] lives in component (c&3) of lane (c>>2) -> compile-time readlane.
  float o = (lane<COUT) ? ldf(bias,lane,f32m) : 0.f;
  #pragma unroll
  for(int c=0;c<CIN;c++){
    float acomp = (c&3)==0 ? ax : ((c&3)==1 ? ay : ((c&3)==2 ? az : aw));
    float ag = __shfl(acomp, c>>2);
    float hv = hs[c];
    u32 p = Wp[(c<<6)|lane];               // zero-padded to 64 lanes, no OOB
    o = fmaf(ag, __uint_as_float(p<<16), o);
    o = fmaf(hv, __uint_as_float(p & 0xffff0000u), o);
  }

  float sq = o*o;                          // lanes >= COUT contribute 0
  #pragma unroll
  for(int d=1; d<64; d<<=1) sq += __shfl_xor(sq, d);
  float r = o * (1.f/fmaxf(sqrtf(sq), 1e-12f));
  if(!LAST) r = fmaxf(r, 0.f);

  if(lane<COUT){
    long oi = (long)node*COUT+lane;
    if(LAST){
      if(f32m) ((float*)outp)[oi] = r;
      else     ((bf16*)outp)[oi]  = __float2bfloat16(r);
    } else {
      hout[oi] = r;
    }
  }
}

// ---------------- launch ----------------

extern "C" void kernel_launch(void* const* d_in, const int* in_sizes, int n_in,
                              void* d_out, int out_size, void* d_ws, size_t ws_size,
                              hipStream_t stream){
  const void* x    = d_in[0];
  const int*  ei   = (const int*)d_in[1];
  const void* ew   = d_in[2];
  const void* embW = d_in[3];
  const void* embB = d_in[4];
  const void *Wl0=d_in[5],  *Wr0=d_in[6],  *b0=d_in[7];
  const void *Wl1=d_in[8],  *Wr1=d_in[9],  *b1=d_in[10];
  const void *Wl2=d_in[11], *Wr2=d_in[12], *b2=d_in[13];
  const void *Wl3=d_in[14], *Wr3=d_in[15], *b3=d_in[16];
  const void *Wlo=d_in[17], *Wro=d_in[18], *bo=d_in[19];

  // 256B-aligned workspace carves (float4 gather targets must be 16B-aligned)
  char* w = (char*)d_ws;
  auto carve = [&](size_t nbytes)->char*{
    char* r = w; w += (nbytes + 255) & ~(size_t)255; return r;
  };
  int*   flags   = (int*)carve(16);
  int*   deg     = (int*)carve((size_t)N_NODES*4);
  int*   cur     = (int*)carve((size_t)N_NODES*4);
  int*   off     = (int*)carve((size_t)(N_NODES+1)*4);
  int*   csr_src = (int*)carve((size_t)N_EDGES*4);
  float* csr_ew  = (float*)carve((size_t)N_EDGES*4);
  u32*   Wp0     = (u32*)carve((size_t)80*64*4);
  u32*   Wp1     = (u32*)carve((size_t)64*64*4);
  u32*   Wp2     = (u32*)carve((size_t)64*64*4);
  u32*   Wp3     = (u32*)carve((size_t)64*64*4);
  u32*   Wpo     = (u32*)carve((size_t)64*64*4);
  float* hA      = (float*)carve((size_t)N_NODES*80*4);  // stride 80 (layer0 in), reused stride 64 later
  float* hB      = (float*)carve((size_t)N_NODES*64*4);  // stride 64

  k_detect<<<1, 256, 0, stream>>>((const u32*)x, ei, flags);
  k_zero2<<<(N_NODES+255)/256, 256, 0, stream>>>(deg, cur);
  k_count<<<N_EDGES/256, 256, 0, stream>>>(ei, flags, deg);
  k_scan <<<1, 1024, 0, stream>>>(deg, off);
  k_fill <<<N_EDGES/256, 256, 0, stream>>>(ei, ew, flags, off, cur, csr_src, csr_ew);

  k_pack<<<20, 256, 0, stream>>>(Wl0, Wr0, flags, 80, 64, Wp0);
  k_pack<<<16, 256, 0, stream>>>(Wl1, Wr1, flags, 64, 64, Wp1);
  k_pack<<<16, 256, 0, stream>>>(Wl2, Wr2, flags, 64, 64, Wp2);
  k_pack<<<16, 256, 0, stream>>>(Wl3, Wr3, flags, 64, 64, Wp3);
  k_pack<<<16, 256, 0, stream>>>(Wlo, Wro, flags, 64, 18, Wpo);

  k_embed<<<(N_NODES+63)/64, 256, 0, stream>>>(x, embW, embB, flags, hA);

  k_sage<80,64,false><<<N_NODES/4, 256, 0, stream>>>(hA, off, csr_src, csr_ew, Wp0, b0, flags, hB, nullptr);
  k_sage<64,64,false><<<N_NODES/4, 256, 0, stream>>>(hB, off, csr_src, csr_ew, Wp1, b1, flags, hA, nullptr);
  k_sage<64,64,false><<<N_NODES/4, 256, 0, stream>>>(hA, off, csr_src, csr_ew, Wp2, b2, flags, hB, nullptr);
  k_sage<64,64,false><<<N_NODES/4, 256, 0, stream>>>(hB, off, csr_src, csr_ew, Wp3, b3, flags, hA, nullptr);
  k_sage<64,18,true ><<<N_NODES/4, 256, 0, stream>>>(hA, off, csr_src, csr_ew, Wpo, bo, flags, nullptr, d_out);
}

// Round 13
// 806.301 us; speedup vs baseline: 1.8637x; 1.1953x over previous
//
#include <hip/hip_runtime.h>
#include <hip/hip_bf16.h>

#define N_NODES 100000
#define N_EDGES 1600000
#define SCAN_BLOCKS ((N_NODES+255)/256)   // 391

using bf16 = __hip_bfloat16;
typedef unsigned int u32;

static __device__ __forceinline__ float b2f(bf16 v){ return __bfloat162float(v); }

// float loader: f32m=1 -> buffer is float32, f32m=0 -> buffer is bf16
static __device__ __forceinline__ float ldf(const void* p, long i, int f32m){
  return f32m ? ((const float*)p)[i] : b2f(((const bf16*)p)[i]);
}

static __device__ __forceinline__ u32 f2bf_rne(float f){
  u32 b = __float_as_uint(f);
  return (b + 0x7fffu + ((b>>16)&1u)) >> 16;
}

// ---------------- dtype detection (device-side, deterministic) ----------------
__global__ void k_detect(const u32* __restrict__ xw, const int* __restrict__ eiw,
                         int* __restrict__ flags){
  __shared__ int s_wild, s_nzodd;
  if(threadIdx.x==0){ s_wild=0; s_nzodd=0; }
  __syncthreads();
  int wild=0, nz=0;
  for(int k=threadIdx.x;k<2048;k+=256){
    u32 w  = xw[k];
    u32 lo = w & 0xffffu;
    int e  = (int)((lo>>7)&0xffu);
    if((lo & 0x7fffu)!=0u && (e<90 || e>160)) wild++;
    if(eiw[2*k+1]!=0) nz++;
  }
  atomicAdd(&s_wild, wild);
  atomicAdd(&s_nzodd, nz);
  __syncthreads();
  if(threadIdx.x==0){
    flags[0] = (s_wild > 512) ? 1 : 0;   // 1: floats are f32
    flags[1] = (s_nzodd == 0) ? 1 : 0;   // 1: indices are int64
  }
}

__global__ void k_zero2(int* __restrict__ a, int* __restrict__ b){
  int i = blockIdx.x*256 + threadIdx.x;
  if(i<N_NODES){ a[i]=0; b[i]=0; }
}

// ---------------- CSR build ----------------

__global__ void k_count(const int* __restrict__ ei, const int* __restrict__ flags,
                        int* __restrict__ deg){
  int e = blockIdx.x*256 + threadIdx.x;
  int i64 = flags[1];
  if(e < N_EDGES){
    long di = i64 ? 2l*(N_EDGES + e) : (long)(N_EDGES + e);
    atomicAdd(&deg[ei[di]], 1);
  }
}

// hierarchical exclusive scan of deg[0..N) -> off, block totals -> bsum
__global__ void k_scan1(const int* __restrict__ deg, int* __restrict__ off,
                        int* __restrict__ bsum){
  const int t = threadIdx.x, lane = t&63, wid = t>>6;
  const int i = blockIdx.x*256 + t;
  int v = (i<N_NODES) ? deg[i] : 0;
  const int orig = v;
  #pragma unroll
  for(int d=1; d<64; d<<=1){ int u = __shfl_up(v,d); if(lane>=d) v += u; }
  __shared__ int wsum[4];
  if(lane==63) wsum[wid] = v;
  __syncthreads();
  int wbase = 0;
  for(int k=0;k<wid;k++) wbase += wsum[k];
  if(i<N_NODES) off[i] = wbase + v - orig;          // block-local exclusive
  if(t==255) bsum[blockIdx.x] = wbase + v;          // block total
}

__global__ void k_scan2(const int* __restrict__ bsum, int* __restrict__ bbase){
  const int t = threadIdx.x, lane = t&63, wid = t>>6; // 512 threads, 8 waves
  int v = (t<SCAN_BLOCKS) ? bsum[t] : 0;
  const int orig = v;
  #pragma unroll
  for(int d=1; d<64; d<<=1){ int u = __shfl_up(v,d); if(lane>=d) v += u; }
  __shared__ int wsum[8];
  if(lane==63) wsum[wid] = v;
  __syncthreads();
  int wbase = 0;
  for(int k=0;k<wid;k++) wbase += wsum[k];
  if(t<SCAN_BLOCKS) bbase[t] = wbase + v - orig;    // exclusive block base
}

__global__ void k_scan3(int* __restrict__ off, const int* __restrict__ bbase){
  const int i = blockIdx.x*256 + threadIdx.x;
  if(i<N_NODES) off[i] += bbase[blockIdx.x];
  if(i==0) off[N_NODES] = N_EDGES;
}

__global__ void k_fill(const int* __restrict__ ei, const void* __restrict__ ew,
                       const int* __restrict__ flags, const int* __restrict__ off,
                       int* __restrict__ cur, int* __restrict__ csr_src,
                       float* __restrict__ csr_ew){
  int e = blockIdx.x*256 + threadIdx.x;
  int i64 = flags[1], f32m = flags[0];
  if(e < N_EDGES){
    int s = ei[i64 ? 2l*e : (long)e];
    int d = ei[i64 ? 2l*(N_EDGES+e) : (long)(N_EDGES+e)];
    int p = atomicAdd(&cur[d], 1);
    int idx = off[d] + p;
    csr_src[idx] = s;
    csr_ew[idx]  = ldf(ew, e, f32m);
  }
}

// ---------------- weight pre-pack: out[c*64+k] = {bf16(Wr), bf16(Wl)} ----------------

__global__ void k_pack(const void* __restrict__ Wl, const void* __restrict__ Wr,
                       const int* __restrict__ flags, int CIN, int COUT,
                       u32* __restrict__ out){
  int i = blockIdx.x*256 + threadIdx.x;
  if(i < CIN*64){
    int c = i>>6, k = i&63;
    u32 v = 0;
    if(k < COUT){
      int f32m = flags[0];
      u32 l = f2bf_rne(ldf(Wl,(long)c*COUT+k,f32m));
      u32 r = f2bf_rne(ldf(Wr,(long)c*COUT+k,f32m));
      v = (r<<16) | l;
    }
    out[i] = v;
  }
}

// ---------------- embedding: tiled LDS GEMM, 64 nodes/block, 4x5 reg tile ----------------

__global__ __launch_bounds__(256,2) void k_embed(const void* __restrict__ x,
                                                 const void* __restrict__ W,
                                                 const void* __restrict__ b,
                                                 const int* __restrict__ flags,
                                                 float* __restrict__ h){
  __shared__ float xs[100][65];     // [channel][node], pad 65 -> conflict-free
  __shared__ float Ws[100*80];
  const int t = threadIdx.x;
  const int n0 = blockIdx.x*64;
  const int f32m = flags[0];
  for(int i=t;i<8000;i+=256) Ws[i]=ldf(W,i,f32m);
  for(int idx=t; idx<6400; idx+=256){
    int n = idx/100, c = idx - n*100;
    float v = (n0+n < N_NODES) ? ldf(x,(long)(n0+n)*100+c,f32m) : 0.f;
    xs[c][n] = v;
  }
  __syncthreads();

  const int ng = t&15, og = t>>4;    // nodes ng*4..+3, outs og*5..+4
  float acc[4][5];
  #pragma unroll
  for(int j=0;j<5;j++){
    float bj = ldf(b, og*5+j, f32m);
    #pragma unroll
    for(int i=0;i<4;i++) acc[i][j] = bj;
  }
  #pragma unroll 2
  for(int c=0;c<100;c++){
    float xv[4];
    #pragma unroll
    for(int i=0;i<4;i++) xv[i] = xs[c][ng*4+i];
    #pragma unroll
    for(int j=0;j<5;j++){
      float wj = Ws[c*80+og*5+j];
      #pragma unroll
      for(int i=0;i<4;i++) acc[i][j] = fmaf(xv[i], wj, acc[i][j]);
    }
  }
  #pragma unroll
  for(int i=0;i<4;i++){
    int n = n0 + ng*4 + i;
    if(n < N_NODES){
      #pragma unroll
      for(int j=0;j<5;j++) h[(long)n*80 + og*5+j] = fmaxf(acc[i][j], 0.f);
    }
  }
}

// ---------------- fused SAGE layer (f32 rows, float4 gather, 4-deep ILP) ----------------
// one wave per node. Gather: CIN/4 lanes per edge read the neighbor row as
// float4; 4 independent row loads in flight. xor/3-way reduce across edge
// groups -> lane q<LPE holds channels 4q..4q+3. Matvec reads that layout
// directly via compile-time readlane broadcasts; self row comes from scalar
// (wave-uniform) loads. Packed bf16 weight pairs from global (L1-resident).
// L2 normalize, relu, store. hin/hout 16B-aligned (ws carves 256B-aligned).

template<int CIN, int COUT, bool LAST>
__global__ __launch_bounds__(256,4) void k_sage(
    const float* __restrict__ hin, const int* __restrict__ off,
    const int* __restrict__ csr_src, const float* __restrict__ csr_ew,
    const u32* __restrict__ Wp, const void* __restrict__ bias,
    const int* __restrict__ flags, float* __restrict__ hout, void* __restrict__ outp)
{
  const int f32m = flags[0];
  const int lane = threadIdx.x&63;
  const int node = blockIdx.x*4 + (threadIdx.x>>6);   // grid covers N_NODES exactly
  constexpr int LPE = CIN/4;                          // lanes per edge-row: 16 or 20
  constexpr int EPW = 64/LPE;                         // edges per wave load: 4 or 3

  const int sub = lane/LPE;                           // edge slot
  const int cl  = lane - sub*LPE;                     // float4-quad within row
  const bool lact = (sub < EPW);

  float ax=0.f, ay=0.f, az=0.f, aw=0.f;
  const int e0 = off[node], e1 = off[node+1];
  for(int base=e0; base<e1; base+=64){
    const int cnt = min(64, e1-base);
    int   sv = (lane<cnt) ? csr_src[base+lane] : 0;
    float wv = LAST ? 1.f : ((lane<cnt) ? csr_ew[base+lane] : 0.f);
    for(int j=0; j<cnt; j+=4*EPW){
      int ei0 = j+sub, ei1 = j+EPW+sub, ei2 = j+2*EPW+sub, ei3 = j+3*EPW+sub;
      bool v0 = lact && (ei0<cnt), v1 = lact && (ei1<cnt);
      bool v2 = lact && (ei2<cnt), v3 = lact && (ei3<cnt);
      int x0 = v0?ei0:0, x1 = v1?ei1:0, x2 = v2?ei2:0, x3 = v3?ei3:0;
      int   s0=__shfl(sv,x0), s1=__shfl(sv,x1), s2=__shfl(sv,x2), s3=__shfl(sv,x3);
      float w0=__shfl(wv,x0)*(v0?1.f:0.f), w1=__shfl(wv,x1)*(v1?1.f:0.f);
      float w2=__shfl(wv,x2)*(v2?1.f:0.f), w3=__shfl(wv,x3)*(v3?1.f:0.f);
      const float4 r0 = *(const float4*)(hin + (long)s0*CIN + 4*cl);
      const float4 r1 = *(const float4*)(hin + (long)s1*CIN + 4*cl);
      const float4 r2 = *(const float4*)(hin + (long)s2*CIN + 4*cl);
      const float4 r3 = *(const float4*)(hin + (long)s3*CIN + 4*cl);
      ax = fmaf(w0,r0.x, fmaf(w1,r1.x, fmaf(w2,r2.x, fmaf(w3,r3.x, ax))));
      ay = fmaf(w0,r0.y, fmaf(w1,r1.y, fmaf(w2,r2.y, fmaf(w3,r3.y, ay))));
      az = fmaf(w0,r0.z, fmaf(w1,r1.z, fmaf(w2,r2.z, fmaf(w3,r3.z, az))));
      aw = fmaf(w0,r0.w, fmaf(w1,r1.w, fmaf(w2,r2.w, fmaf(w3,r3.w, aw))));
    }
  }

  // reduce across edge groups: lane q<LPE ends with full sums for quad q
  if(EPW == 4){
    ax += __shfl_xor(ax,16); ax += __shfl_xor(ax,32);
    ay += __shfl_xor(ay,16); ay += __shfl_xor(ay,32);
    az += __shfl_xor(az,16); az += __shfl_xor(az,32);
    aw += __shfl_xor(aw,16); aw += __shfl_xor(aw,32);
  } else {                       // EPW==3: groups at lanes 0..19 / 20..39 / 40..59
    ax = __shfl(ax,cl) + __shfl(ax,cl+20) + __shfl(ax,cl+40);
    ay = __shfl(ay,cl) + __shfl(ay,cl+20) + __shfl(ay,cl+40);
    az = __shfl(az,cl) + __shfl(az,cl+20) + __shfl(az,cl+40);
    aw = __shfl(aw,cl) + __shfl(aw,cl+20) + __shfl(aw,cl+40);
  }
  const float inv = 1.f/fmaxf((float)(e1-e0), 1.f);
  ax *= inv; ay *= inv; az *= inv; aw *= inv;

  // self row via wave-uniform scalar loads
  const float* hs = hin + (long)__builtin_amdgcn_readfirstlane(node)*CIN;

  // matvec: o[lane] = bias[lane] + sum_c agg[c]*Wl[c][lane] + h[c]*Wr[c][lane]
  // agg[c] lives in component (c&3) of lane (c>>2) -> compile-time readlane.
  float o = (lane<COUT) ? ldf(bias,lane,f32m) : 0.f;
  #pragma unroll
  for(int c=0;c<CIN;c++){
    float acomp = (c&3)==0 ? ax : ((c&3)==1 ? ay : ((c&3)==2 ? az : aw));
    float ag = __shfl(acomp, c>>2);
    float hv = hs[c];
    u32 p = Wp[(c<<6)|lane];               // zero-padded to 64 lanes, no OOB
    o = fmaf(ag, __uint_as_float(p<<16), o);
    o = fmaf(hv, __uint_as_float(p & 0xffff0000u), o);
  }

  float sq = o*o;                          // lanes >= COUT contribute 0
  #pragma unroll
  for(int d=1; d<64; d<<=1) sq += __shfl_xor(sq, d);
  float r = o * (1.f/fmaxf(sqrtf(sq), 1e-12f));
  if(!LAST) r = fmaxf(r, 0.f);

  if(lane<COUT){
    long oi = (long)node*COUT+lane;
    if(LAST){
      if(f32m) ((float*)outp)[oi] = r;
      else     ((bf16*)outp)[oi]  = __float2bfloat16(r);
    } else {
      hout[oi] = r;
    }
  }
}

// ---------------- launch ----------------

extern "C" void kernel_launch(void* const* d_in, const int* in_sizes, int n_in,
                              void* d_out, int out_size, void* d_ws, size_t ws_size,
                              hipStream_t stream){
  const void* x    = d_in[0];
  const int*  ei   = (const int*)d_in[1];
  const void* ew   = d_in[2];
  const void* embW = d_in[3];
  const void* embB = d_in[4];
  const void *Wl0=d_in[5],  *Wr0=d_in[6],  *b0=d_in[7];
  const void *Wl1=d_in[8],  *Wr1=d_in[9],  *b1=d_in[10];
  const void *Wl2=d_in[11], *Wr2=d_in[12], *b2=d_in[13];
  const void *Wl3=d_in[14], *Wr3=d_in[15], *b3=d_in[16];
  const void *Wlo=d_in[17], *Wro=d_in[18], *bo=d_in[19];

  // 256B-aligned workspace carves (float4 gather targets must be 16B-aligned)
  char* w = (char*)d_ws;
  auto carve = [&](size_t nbytes)->char*{
    char* r = w; w += (nbytes + 255) & ~(size_t)255; return r;
  };
  int*   flags   = (int*)carve(16);
  int*   deg     = (int*)carve((size_t)N_NODES*4);
  int*   cur     = (int*)carve((size_t)N_NODES*4);
  int*   off     = (int*)carve((size_t)(N_NODES+1)*4);
  int*   bsum    = (int*)carve((size_t)SCAN_BLOCKS*4);
  int*   bbase   = (int*)carve((size_t)SCAN_BLOCKS*4);
  int*   csr_src = (int*)carve((size_t)N_EDGES*4);
  float* csr_ew  = (float*)carve((size_t)N_EDGES*4);
  u32*   Wp0     = (u32*)carve((size_t)80*64*4);
  u32*   Wp1     = (u32*)carve((size_t)64*64*4);
  u32*   Wp2     = (u32*)carve((size_t)64*64*4);
  u32*   Wp3     = (u32*)carve((size_t)64*64*4);
  u32*   Wpo     = (u32*)carve((size_t)64*64*4);
  float* hA      = (float*)carve((size_t)N_NODES*80*4);  // stride 80 (layer0 in), reused stride 64 later
  float* hB      = (float*)carve((size_t)N_NODES*64*4);  // stride 64

  k_detect<<<1, 256, 0, stream>>>((const u32*)x, ei, flags);
  k_zero2<<<(N_NODES+255)/256, 256, 0, stream>>>(deg, cur);
  k_count<<<N_EDGES/256, 256, 0, stream>>>(ei, flags, deg);
  k_scan1<<<SCAN_BLOCKS, 256, 0, stream>>>(deg, off, bsum);
  k_scan2<<<1, 512, 0, stream>>>(bsum, bbase);
  k_scan3<<<SCAN_BLOCKS, 256, 0, stream>>>(off, bbase);
  k_fill <<<N_EDGES/256, 256, 0, stream>>>(ei, ew, flags, off, cur, csr_src, csr_ew);

  k_pack<<<20, 256, 0, stream>>>(Wl0, Wr0, flags, 80, 64, Wp0);
  k_pack<<<16, 256, 0, stream>>>(Wl1, Wr1, flags, 64, 64, Wp1);
  k_pack<<<16, 256, 0, stream>>>(Wl2, Wr2, flags, 64, 64, Wp2);
  k_pack<<<16, 256, 0, stream>>>(Wl3, Wr3, flags, 64, 64, Wp3);
  k_pack<<<16, 256, 0, stream>>>(Wlo, Wro, flags, 64, 18, Wpo);

  k_embed<<<(N_NODES+63)/64, 256, 0, stream>>>(x, embW, embB, flags, hA);

  k_sage<80,64,false><<<N_NODES/4, 256, 0, stream>>>(hA, off, csr_src, csr_ew, Wp0, b0, flags, hB, nullptr);
  k_sage<64,64,false><<<N_NODES/4, 256, 0, stream>>>(hB, off, csr_src, csr_ew, Wp1, b1, flags, hA, nullptr);
  k_sage<64,64,false><<<N_NODES/4, 256, 0, stream>>>(hA, off, csr_src, csr_ew, Wp2, b2, flags, hB, nullptr);
  k_sage<64,64,false><<<N_NODES/4, 256, 0, stream>>>(hB, off, csr_src, csr_ew, Wp3, b3, flags, hA, nullptr);
  k_sage<64,18,true ><<<N_NODES/4, 256, 0, stream>>>(hA, off, csr_src, csr_ew, Wpo, bo, flags, nullptr, d_out);
}

// Round 14
// 670.260 us; speedup vs baseline: 2.2419x; 1.2030x over previous
//
#include <hip/hip_runtime.h>
#include <hip/hip_bf16.h>

#define N_NODES 100000
#define N_EDGES 1600000
#define SCAN_BLOCKS ((N_NODES+255)/256)   // 391

using bf16 = __hip_bfloat16;
typedef unsigned int u32;
typedef __attribute__((ext_vector_type(8))) short short8;
typedef __attribute__((ext_vector_type(4))) float f32x4;

static __device__ __forceinline__ float b2f(bf16 v){ return __bfloat162float(v); }

// float loader: f32m=1 -> buffer is float32, f32m=0 -> buffer is bf16
static __device__ __forceinline__ float ldf(const void* p, long i, int f32m){
  return f32m ? ((const float*)p)[i] : b2f(((const bf16*)p)[i]);
}

static __device__ __forceinline__ u32 f2bf_rne(float f){
  u32 b = __float_as_uint(f);
  return (b + 0x7fffu + ((b>>16)&1u)) >> 16;
}

// ---------------- dtype detection (device-side, deterministic) ----------------
__global__ void k_detect(const u32* __restrict__ xw, const int* __restrict__ eiw,
                         int* __restrict__ flags){
  __shared__ int s_wild, s_nzodd;
  if(threadIdx.x==0){ s_wild=0; s_nzodd=0; }
  __syncthreads();
  int wild=0, nz=0;
  for(int k=threadIdx.x;k<2048;k+=256){
    u32 w  = xw[k];
    u32 lo = w & 0xffffu;
    int e  = (int)((lo>>7)&0xffu);
    if((lo & 0x7fffu)!=0u && (e<90 || e>160)) wild++;
    if(eiw[2*k+1]!=0) nz++;
  }
  atomicAdd(&s_wild, wild);
  atomicAdd(&s_nzodd, nz);
  __syncthreads();
  if(threadIdx.x==0){
    flags[0] = (s_wild > 512) ? 1 : 0;   // 1: floats are f32
    flags[1] = (s_nzodd == 0) ? 1 : 0;   // 1: indices are int64
  }
}

__global__ void k_zero2(int* __restrict__ a, int* __restrict__ b){
  int i = blockIdx.x*256 + threadIdx.x;
  if(i<N_NODES){ a[i]=0; b[i]=0; }
}

// ---------------- CSR build ----------------

__global__ void k_count(const int* __restrict__ ei, const int* __restrict__ flags,
                        int* __restrict__ deg){
  int e = blockIdx.x*256 + threadIdx.x;
  int i64 = flags[1];
  if(e < N_EDGES){
    long di = i64 ? 2l*(N_EDGES + e) : (long)(N_EDGES + e);
    atomicAdd(&deg[ei[di]], 1);
  }
}

// hierarchical exclusive scan of deg[0..N) -> off, block totals -> bsum
__global__ void k_scan1(const int* __restrict__ deg, int* __restrict__ off,
                        int* __restrict__ bsum){
  const int t = threadIdx.x, lane = t&63, wid = t>>6;
  const int i = blockIdx.x*256 + t;
  int v = (i<N_NODES) ? deg[i] : 0;
  const int orig = v;
  #pragma unroll
  for(int d=1; d<64; d<<=1){ int u = __shfl_up(v,d); if(lane>=d) v += u; }
  __shared__ int wsum[4];
  if(lane==63) wsum[wid] = v;
  __syncthreads();
  int wbase = 0;
  for(int k=0;k<wid;k++) wbase += wsum[k];
  if(i<N_NODES) off[i] = wbase + v - orig;          // block-local exclusive
  if(t==255) bsum[blockIdx.x] = wbase + v;          // block total
}

__global__ void k_scan2(const int* __restrict__ bsum, int* __restrict__ bbase){
  const int t = threadIdx.x, lane = t&63, wid = t>>6; // 512 threads, 8 waves
  int v = (t<SCAN_BLOCKS) ? bsum[t] : 0;
  const int orig = v;
  #pragma unroll
  for(int d=1; d<64; d<<=1){ int u = __shfl_up(v,d); if(lane>=d) v += u; }
  __shared__ int wsum[8];
  if(lane==63) wsum[wid] = v;
  __syncthreads();
  int wbase = 0;
  for(int k=0;k<wid;k++) wbase += wsum[k];
  if(t<SCAN_BLOCKS) bbase[t] = wbase + v - orig;    // exclusive block base
}

__global__ void k_scan3(int* __restrict__ off, const int* __restrict__ bbase){
  const int i = blockIdx.x*256 + threadIdx.x;
  if(i<N_NODES) off[i] += bbase[blockIdx.x];
  if(i==0) off[N_NODES] = N_EDGES;
}

__global__ void k_fill(const int* __restrict__ ei, const void* __restrict__ ew,
                       const int* __restrict__ flags, const int* __restrict__ off,
                       int* __restrict__ cur, int* __restrict__ csr_src,
                       float* __restrict__ csr_ew){
  int e = blockIdx.x*256 + threadIdx.x;
  int i64 = flags[1], f32m = flags[0];
  if(e < N_EDGES){
    int s = ei[i64 ? 2l*e : (long)e];
    int d = ei[i64 ? 2l*(N_EDGES+e) : (long)(N_EDGES+e)];
    int p = atomicAdd(&cur[d], 1);
    int idx = off[d] + p;
    csr_src[idx] = s;
    csr_ew[idx]  = ldf(ew, e, f32m);
  }
}

// ---------------- B-fragment pre-pack for MFMA ----------------
// Wfull[K x COUT]: rows 0..khalf-1 = Wl (agg, zero-padded past CIN),
// rows khalf.. = Wr (h). Fragment: out[((kt*NT+nt)*64 + l)*8 + j] =
// Wfull[kt*32 + (l>>4)*8 + j][nt*16 + (l&15)]  (bf16, zero outside).

__global__ void k_packb(const void* __restrict__ Wl, const void* __restrict__ Wr,
                        const int* __restrict__ flags, int CIN, int COUT,
                        int KT, int NT, short* __restrict__ out){
  int idx = blockIdx.x*256 + threadIdx.x;
  int total = KT*NT*512;
  if(idx < total){
    int jj = idx & 7;
    int l  = (idx>>3) & 63;
    int tile = idx >> 9;             // kt*NT + nt
    int nt = tile % NT, kt = tile / NT;
    int k   = kt*32 + ((l>>4)<<3) + jj;
    int col = nt*16 + (l&15);
    int khalf = (KT/2)*32;
    float v = 0.f;
    if(col < COUT){
      int f32m = flags[0];
      if(k < khalf){ if(k < CIN) v = ldf(Wl,(long)k*COUT+col,f32m); }
      else { int ch = k - khalf; if(ch < CIN) v = ldf(Wr,(long)ch*COUT+col,f32m); }
    }
    out[idx] = (short)f2bf_rne(v);
  }
}

// ---------------- embedding: tiled LDS GEMM, 64 nodes/block, 4x5 reg tile ----------------

__global__ __launch_bounds__(256,2) void k_embed(const void* __restrict__ x,
                                                 const void* __restrict__ W,
                                                 const void* __restrict__ b,
                                                 const int* __restrict__ flags,
                                                 float* __restrict__ h){
  __shared__ float xs[100][65];     // [channel][node], pad 65 -> conflict-free
  __shared__ float Ws[100*80];
  const int t = threadIdx.x;
  const int n0 = blockIdx.x*64;
  const int f32m = flags[0];
  for(int i=t;i<8000;i+=256) Ws[i]=ldf(W,i,f32m);
  for(int idx=t; idx<6400; idx+=256){
    int n = idx/100, c = idx - n*100;
    float v = (n0+n < N_NODES) ? ldf(x,(long)(n0+n)*100+c,f32m) : 0.f;
    xs[c][n] = v;
  }
  __syncthreads();

  const int ng = t&15, og = t>>4;    // nodes ng*4..+3, outs og*5..+4
  float acc[4][5];
  #pragma unroll
  for(int j=0;j<5;j++){
    float bj = ldf(b, og*5+j, f32m);
    #pragma unroll
    for(int i=0;i<4;i++) acc[i][j] = bj;
  }
  #pragma unroll 2
  for(int c=0;c<100;c++){
    float xv[4];
    #pragma unroll
    for(int i=0;i<4;i++) xv[i] = xs[c][ng*4+i];
    #pragma unroll
    for(int j=0;j<5;j++){
      float wj = Ws[c*80+og*5+j];
      #pragma unroll
      for(int i=0;i<4;i++) acc[i][j] = fmaf(xv[i], wj, acc[i][j]);
    }
  }
  #pragma unroll
  for(int i=0;i<4;i++){
    int n = n0 + ng*4 + i;
    if(n < N_NODES){
      #pragma unroll
      for(int j=0;j<5;j++) h[(long)n*80 + og*5+j] = fmaxf(acc[i][j], 0.f);
    }
  }
}

// ---------------- fused SAGE layer: f32 gather + MFMA matvec ----------------
// block = 4 waves x 16 nodes. Phase 1 (per wave): for each of its 16 nodes,
// float4-gather (4-deep ILP) + reduce -> agg quads; write A-row
// [agg bf16 | h bf16] (K = KT*32) into LDS with XOR swizzle byte^=(row&7)<<4.
// Phase 2 (per wave, wave-local LDS deps, no barrier): C[16xCOUT] = A·Wb via
// mfma_f32_16x16x32_bf16 (A: row=lane&15,k=(lane>>4)*8+j; B frag preloaded
// per-lane; C: col=lane&15,row=(lane>>4)*4+reg). Bias in acc init; L2-norm
// via 16-lane-group shfl_xor; relu; store.

template<int CIN, int COUT, bool LAST>
__global__ __launch_bounds__(256,4) void k_sage(
    const float* __restrict__ hin, const int* __restrict__ off,
    const int* __restrict__ csr_src, const float* __restrict__ csr_ew,
    const short* __restrict__ Wb, const void* __restrict__ bias,
    const int* __restrict__ flags, float* __restrict__ hout, void* __restrict__ outp)
{
  constexpr int KHT  = (CIN+31)/32;          // K-tiles per half: 2 or 3
  constexpr int KT   = 2*KHT;                // 4 or 6
  constexpr int NT   = (COUT+15)/16;         // 4 or 2
  constexpr int ROWB = KT*32*2;              // 256 or 384 bytes per A-row
  constexpr int LPE  = CIN/4;                // 16 or 20
  constexpr int EPW  = 64/LPE;               // 4 or 3

  __shared__ char smem[4*16*ROWB];

  const int f32m = flags[0];
  const int lane = threadIdx.x&63, wid = threadIdx.x>>6;
  const int wnode0 = blockIdx.x*64 + wid*16;
  char* lds = smem + wid*16*ROWB;

  const int sub = lane/LPE;
  const int cl  = lane - sub*LPE;
  const bool lact = (sub < EPW);

  // ---- phase 1: gather + A-row staging ----
  for(int tt=0; tt<16; ++tt){
    const int node = wnode0 + tt;
    if(node >= N_NODES) continue;

    float ax=0.f, ay=0.f, az=0.f, aw=0.f;
    const int e0 = off[node], e1 = off[node+1];
    for(int base=e0; base<e1; base+=64){
      const int cnt = min(64, e1-base);
      int   sv = (lane<cnt) ? csr_src[base+lane] : 0;
      float wv = LAST ? 1.f : ((lane<cnt) ? csr_ew[base+lane] : 0.f);
      for(int j=0; j<cnt; j+=4*EPW){
        int ei0 = j+sub, ei1 = j+EPW+sub, ei2 = j+2*EPW+sub, ei3 = j+3*EPW+sub;
        bool v0 = lact && (ei0<cnt), v1 = lact && (ei1<cnt);
        bool v2 = lact && (ei2<cnt), v3 = lact && (ei3<cnt);
        int x0 = v0?ei0:0, x1 = v1?ei1:0, x2 = v2?ei2:0, x3 = v3?ei3:0;
        int   s0=__shfl(sv,x0), s1=__shfl(sv,x1), s2=__shfl(sv,x2), s3=__shfl(sv,x3);
        float w0=__shfl(wv,x0)*(v0?1.f:0.f), w1=__shfl(wv,x1)*(v1?1.f:0.f);
        float w2=__shfl(wv,x2)*(v2?1.f:0.f), w3=__shfl(wv,x3)*(v3?1.f:0.f);
        const float4 r0 = *(const float4*)(hin + (long)s0*CIN + 4*cl);
        const float4 r1 = *(const float4*)(hin + (long)s1*CIN + 4*cl);
        const float4 r2 = *(const float4*)(hin + (long)s2*CIN + 4*cl);
        const float4 r3 = *(const float4*)(hin + (long)s3*CIN + 4*cl);
        ax = fmaf(w0,r0.x, fmaf(w1,r1.x, fmaf(w2,r2.x, fmaf(w3,r3.x, ax))));
        ay = fmaf(w0,r0.y, fmaf(w1,r1.y, fmaf(w2,r2.y, fmaf(w3,r3.y, ay))));
        az = fmaf(w0,r0.z, fmaf(w1,r1.z, fmaf(w2,r2.z, fmaf(w3,r3.z, az))));
        aw = fmaf(w0,r0.w, fmaf(w1,r1.w, fmaf(w2,r2.w, fmaf(w3,r3.w, aw))));
      }
    }

    if(EPW == 4){
      ax += __shfl_xor(ax,16); ax += __shfl_xor(ax,32);
      ay += __shfl_xor(ay,16); ay += __shfl_xor(ay,32);
      az += __shfl_xor(az,16); az += __shfl_xor(az,32);
      aw += __shfl_xor(aw,16); aw += __shfl_xor(aw,32);
    } else {
      ax = __shfl(ax,cl) + __shfl(ax,cl+20) + __shfl(ax,cl+40);
      ay = __shfl(ay,cl) + __shfl(ay,cl+20) + __shfl(ay,cl+40);
      az = __shfl(az,cl) + __shfl(az,cl+20) + __shfl(az,cl+40);
      aw = __shfl(aw,cl) + __shfl(aw,cl+20) + __shfl(aw,cl+40);
    }
    const float inv = 1.f/fmaxf((float)(e1-e0), 1.f);

    const int sx = (tt&7)<<4;                       // row XOR swizzle
    if(lane < LPE){                                 // agg: bytes 8*lane..+7
      u32 lo = f2bf_rne(ax*inv) | (f2bf_rne(ay*inv)<<16);
      u32 hi = f2bf_rne(az*inv) | (f2bf_rne(aw*inv)<<16);
      int ob = tt*ROWB + lane*8;
      *(uint2*)(lds + (ob^sx)) = make_uint2(lo,hi);
    }
    const float* hs = hin + (long)__builtin_amdgcn_readfirstlane(node)*CIN;
    if(lane < CIN/2){                               // h: bytes KHT*64 + 4*lane
      float2 hv = *(const float2*)(hs + 2*lane);
      u32 pk = f2bf_rne(hv.x) | (f2bf_rne(hv.y)<<16);
      int ob = tt*ROWB + KHT*64 + lane*4;
      *(u32*)(lds + (ob^sx)) = pk;
    }
    if(CIN==80){                                    // zero K-padding
      if(lane>=20 && lane<24){
        int ob = tt*ROWB + 160 + (lane-20)*8;
        *(uint2*)(lds + (ob^sx)) = make_uint2(0u,0u);
      }
      if(lane>=40 && lane<48){
        int ob = tt*ROWB + 352 + (lane-40)*4;
        *(u32*)(lds + (ob^sx)) = 0u;
      }
    }
  }

  // ---- phase 2: MFMA matvec (wave-local LDS reads) ----
  f32x4 acc[NT];
  #pragma unroll
  for(int nt=0; nt<NT; ++nt){
    int col = nt*16 + (lane&15);
    float bv = (col<COUT) ? ldf(bias,col,f32m) : 0.f;
    acc[nt] = (f32x4){bv,bv,bv,bv};
  }
  const int arow = lane&15, kgrp = lane>>4;
  #pragma unroll
  for(int kt=0; kt<KT; ++kt){
    int ob = arow*ROWB + kt*64 + kgrp*16;
    short8 a8 = *(const short8*)(lds + (ob ^ ((arow&7)<<4)));
    #pragma unroll
    for(int nt=0; nt<NT; ++nt){
      short8 b8 = *(const short8*)(Wb + ((long)(kt*NT+nt)*64 + lane)*8);
      acc[nt] = __builtin_amdgcn_mfma_f32_16x16x32_bf16(a8, b8, acc[nt], 0,0,0);
    }
  }

  // ---- epilogue: L2-norm per row, relu, store ----
  float sq[4];
  #pragma unroll
  for(int r=0;r<4;r++){
    float s = 0.f;
    #pragma unroll
    for(int nt=0;nt<NT;nt++){ float v = acc[nt][r]; s = fmaf(v,v,s); }
    #pragma unroll
    for(int d=1; d<16; d<<=1) s += __shfl_xor(s, d);
    sq[r] = s;
  }
  #pragma unroll
  for(int r=0;r<4;r++){
    float rn = 1.f/fmaxf(sqrtf(sq[r]), 1e-12f);
    const int node = wnode0 + 4*(lane>>4) + r;
    #pragma unroll
    for(int nt=0;nt<NT;nt++){
      int col = nt*16 + (lane&15);
      float v = acc[nt][r]*rn;
      if(!LAST) v = fmaxf(v,0.f);
      if(node < N_NODES && col < COUT){
        if(LAST){
          long oi = (long)node*COUT + col;
          if(f32m) ((float*)outp)[oi] = v;
          else     ((bf16*)outp)[oi]  = __float2bfloat16(v);
        } else {
          hout[(long)node*64 + col] = v;
        }
      }
    }
  }
}

// ---------------- launch ----------------

extern "C" void kernel_launch(void* const* d_in, const int* in_sizes, int n_in,
                              void* d_out, int out_size, void* d_ws, size_t ws_size,
                              hipStream_t stream){
  const void* x    = d_in[0];
  const int*  ei   = (const int*)d_in[1];
  const void* ew   = d_in[2];
  const void* embW = d_in[3];
  const void* embB = d_in[4];
  const void *Wl0=d_in[5],  *Wr0=d_in[6],  *b0=d_in[7];
  const void *Wl1=d_in[8],  *Wr1=d_in[9],  *b1=d_in[10];
  const void *Wl2=d_in[11], *Wr2=d_in[12], *b2=d_in[13];
  const void *Wl3=d_in[14], *Wr3=d_in[15], *b3=d_in[16];
  const void *Wlo=d_in[17], *Wro=d_in[18], *bo=d_in[19];

  // 256B-aligned workspace carves (float4/short8 targets must be 16B-aligned)
  char* w = (char*)d_ws;
  auto carve = [&](size_t nbytes)->char*{
    char* r = w; w += (nbytes + 255) & ~(size_t)255; return r;
  };
  int*   flags   = (int*)carve(16);
  int*   deg     = (int*)carve((size_t)N_NODES*4);
  int*   cur     = (int*)carve((size_t)N_NODES*4);
  int*   off     = (int*)carve((size_t)(N_NODES+1)*4);
  int*   bsum    = (int*)carve((size_t)SCAN_BLOCKS*4);
  int*   bbase   = (int*)carve((size_t)SCAN_BLOCKS*4);
  int*   csr_src = (int*)carve((size_t)N_EDGES*4);
  float* csr_ew  = (float*)carve((size_t)N_EDGES*4);
  short* Wb0     = (short*)carve((size_t)6*4*512*2);
  short* Wb1     = (short*)carve((size_t)4*4*512*2);
  short* Wb2     = (short*)carve((size_t)4*4*512*2);
  short* Wb3     = (short*)carve((size_t)4*4*512*2);
  short* Wbo     = (short*)carve((size_t)4*2*512*2);
  float* hA      = (float*)carve((size_t)N_NODES*80*4);  // stride 80 (layer0 in), reused stride 64 later
  float* hB      = (float*)carve((size_t)N_NODES*64*4);  // stride 64

  k_detect<<<1, 256, 0, stream>>>((const u32*)x, ei, flags);
  k_zero2<<<(N_NODES+255)/256, 256, 0, stream>>>(deg, cur);
  k_count<<<N_EDGES/256, 256, 0, stream>>>(ei, flags, deg);
  k_scan1<<<SCAN_BLOCKS, 256, 0, stream>>>(deg, off, bsum);
  k_scan2<<<1, 512, 0, stream>>>(bsum, bbase);
  k_scan3<<<SCAN_BLOCKS, 256, 0, stream>>>(off, bbase);
  k_fill <<<N_EDGES/256, 256, 0, stream>>>(ei, ew, flags, off, cur, csr_src, csr_ew);

  k_packb<<<48, 256, 0, stream>>>(Wl0, Wr0, flags, 80, 64, 6, 4, Wb0);
  k_packb<<<32, 256, 0, stream>>>(Wl1, Wr1, flags, 64, 64, 4, 4, Wb1);
  k_packb<<<32, 256, 0, stream>>>(Wl2, Wr2, flags, 64, 64, 4, 4, Wb2);
  k_packb<<<32, 256, 0, stream>>>(Wl3, Wr3, flags, 64, 64, 4, 4, Wb3);
  k_packb<<<16, 256, 0, stream>>>(Wlo, Wro, flags, 64, 18, 4, 2, Wbo);

  k_embed<<<(N_NODES+63)/64, 256, 0, stream>>>(x, embW, embB, flags, hA);

  const int NBLK = (N_NODES+63)/64;   // 1563
  k_sage<80,64,false><<<NBLK, 256, 0, stream>>>(hA, off, csr_src, csr_ew, Wb0, b0, flags, hB, nullptr);
  k_sage<64,64,false><<<NBLK, 256, 0, stream>>>(hB, off, csr_src, csr_ew, Wb1, b1, flags, hA, nullptr);
  k_sage<64,64,false><<<NBLK, 256, 0, stream>>>(hA, off, csr_src, csr_ew, Wb2, b2, flags, hB, nullptr);
  k_sage<64,64,false><<<NBLK, 256, 0, stream>>>(hB, off, csr_src, csr_ew, Wb3, b3, flags, hA, nullptr);
  k_sage<64,18,true ><<<NBLK, 256, 0, stream>>>(hA, off, csr_src, csr_ew, Wbo, bo, flags, nullptr, d_out);
}

// Round 15
// 651.222 us; speedup vs baseline: 2.3075x; 1.0292x over previous
//
#include <hip/hip_runtime.h>
#include <hip/hip_bf16.h>

#define N_NODES 100000
#define N_EDGES 1600000
#define SCAN_BLOCKS ((N_NODES+255)/256)   // 391

using bf16 = __hip_bfloat16;
typedef unsigned int u32;
typedef __attribute__((ext_vector_type(8))) short short8;
typedef __attribute__((ext_vector_type(4))) float f32x4;

static __device__ __forceinline__ float b2f(bf16 v){ return __bfloat162float(v); }

// float loader: f32m=1 -> buffer is float32, f32m=0 -> buffer is bf16
static __device__ __forceinline__ float ldf(const void* p, long i, int f32m){
  return f32m ? ((const float*)p)[i] : b2f(((const bf16*)p)[i]);
}

static __device__ __forceinline__ u32 f2bf_rne(float f){
  u32 b = __float_as_uint(f);
  return (b + 0x7fffu + ((b>>16)&1u)) >> 16;
}

// ---------------- dtype detection (device-side, deterministic) ----------------
__global__ void k_detect(const u32* __restrict__ xw, const int* __restrict__ eiw,
                         int* __restrict__ flags){
  __shared__ int s_wild, s_nzodd;
  if(threadIdx.x==0){ s_wild=0; s_nzodd=0; }
  __syncthreads();
  int wild=0, nz=0;
  for(int k=threadIdx.x;k<2048;k+=256){
    u32 w  = xw[k];
    u32 lo = w & 0xffffu;
    int e  = (int)((lo>>7)&0xffu);
    if((lo & 0x7fffu)!=0u && (e<90 || e>160)) wild++;
    if(eiw[2*k+1]!=0) nz++;
  }
  atomicAdd(&s_wild, wild);
  atomicAdd(&s_nzodd, nz);
  __syncthreads();
  if(threadIdx.x==0){
    flags[0] = (s_wild > 512) ? 1 : 0;   // 1: floats are f32
    flags[1] = (s_nzodd == 0) ? 1 : 0;   // 1: indices are int64
  }
}

__global__ void k_zero2(int* __restrict__ a, int* __restrict__ b){
  int i = blockIdx.x*256 + threadIdx.x;
  if(i<N_NODES){ a[i]=0; b[i]=0; }
}

// ---------------- CSR build ----------------

__global__ void k_count(const int* __restrict__ ei, const int* __restrict__ flags,
                        int* __restrict__ deg){
  int e = blockIdx.x*256 + threadIdx.x;
  int i64 = flags[1];
  if(e < N_EDGES){
    long di = i64 ? 2l*(N_EDGES + e) : (long)(N_EDGES + e);
    atomicAdd(&deg[ei[di]], 1);
  }
}

// hierarchical exclusive scan of deg[0..N) -> off, block totals -> bsum
__global__ void k_scan1(const int* __restrict__ deg, int* __restrict__ off,
                        int* __restrict__ bsum){
  const int t = threadIdx.x, lane = t&63, wid = t>>6;
  const int i = blockIdx.x*256 + t;
  int v = (i<N_NODES) ? deg[i] : 0;
  const int orig = v;
  #pragma unroll
  for(int d=1; d<64; d<<=1){ int u = __shfl_up(v,d); if(lane>=d) v += u; }
  __shared__ int wsum[4];
  if(lane==63) wsum[wid] = v;
  __syncthreads();
  int wbase = 0;
  for(int k=0;k<wid;k++) wbase += wsum[k];
  if(i<N_NODES) off[i] = wbase + v - orig;          // block-local exclusive
  if(t==255) bsum[blockIdx.x] = wbase + v;          // block total
}

__global__ void k_scan2(const int* __restrict__ bsum, int* __restrict__ bbase){
  const int t = threadIdx.x, lane = t&63, wid = t>>6; // 512 threads, 8 waves
  int v = (t<SCAN_BLOCKS) ? bsum[t] : 0;
  const int orig = v;
  #pragma unroll
  for(int d=1; d<64; d<<=1){ int u = __shfl_up(v,d); if(lane>=d) v += u; }
  __shared__ int wsum[8];
  if(lane==63) wsum[wid] = v;
  __syncthreads();
  int wbase = 0;
  for(int k=0;k<wid;k++) wbase += wsum[k];
  if(t<SCAN_BLOCKS) bbase[t] = wbase + v - orig;    // exclusive block base
}

__global__ void k_scan3(int* __restrict__ off, const int* __restrict__ bbase){
  const int i = blockIdx.x*256 + threadIdx.x;
  if(i<N_NODES) off[i] += bbase[blockIdx.x];
  if(i==0) off[N_NODES] = N_EDGES;
}

// fill interleaved CSR payload: one 8B store per edge {src, ew_f32_bits}
__global__ void k_fill(const int* __restrict__ ei, const void* __restrict__ ew,
                       const int* __restrict__ flags, const int* __restrict__ off,
                       int* __restrict__ cur, uint2* __restrict__ csr){
  int e = blockIdx.x*256 + threadIdx.x;
  int i64 = flags[1], f32m = flags[0];
  if(e < N_EDGES){
    int s = ei[i64 ? 2l*e : (long)e];
    int d = ei[i64 ? 2l*(N_EDGES+e) : (long)(N_EDGES+e)];
    int p = atomicAdd(&cur[d], 1);
    int idx = off[d] + p;
    csr[idx] = make_uint2((u32)s, __float_as_uint(ldf(ew, e, f32m)));
  }
}

// ---------------- B-fragment pre-pack for MFMA ----------------
// Wfull[K x COUT]: rows 0..khalf-1 = Wl (agg, zero-padded past CIN),
// rows khalf.. = Wr (h). Fragment: out[((kt*NT+nt)*64 + l)*8 + j] =
// Wfull[kt*32 + (l>>4)*8 + j][nt*16 + (l&15)]  (bf16, zero outside).

__global__ void k_packb(const void* __restrict__ Wl, const void* __restrict__ Wr,
                        const int* __restrict__ flags, int CIN, int COUT,
                        int KT, int NT, short* __restrict__ out){
  int idx = blockIdx.x*256 + threadIdx.x;
  int total = KT*NT*512;
  if(idx < total){
    int jj = idx & 7;
    int l  = (idx>>3) & 63;
    int tile = idx >> 9;             // kt*NT + nt
    int nt = tile % NT, kt = tile / NT;
    int k   = kt*32 + ((l>>4)<<3) + jj;
    int col = nt*16 + (l&15);
    int khalf = (KT/2)*32;
    float v = 0.f;
    if(col < COUT){
      int f32m = flags[0];
      if(k < khalf){ if(k < CIN) v = ldf(Wl,(long)k*COUT+col,f32m); }
      else { int ch = k - khalf; if(ch < CIN) v = ldf(Wr,(long)ch*COUT+col,f32m); }
    }
    out[idx] = (short)f2bf_rne(v);
  }
}

// ---------------- embedding: tiled LDS GEMM, 64 nodes/block, 4x5 reg tile ----------------

__global__ __launch_bounds__(256,2) void k_embed(const void* __restrict__ x,
                                                 const void* __restrict__ W,
                                                 const void* __restrict__ b,
                                                 const int* __restrict__ flags,
                                                 float* __restrict__ h){
  __shared__ float xs[100][65];     // [channel][node], pad 65 -> conflict-free
  __shared__ float Ws[100*80];
  const int t = threadIdx.x;
  const int n0 = blockIdx.x*64;
  const int f32m = flags[0];
  for(int i=t;i<8000;i+=256) Ws[i]=ldf(W,i,f32m);
  for(int idx=t; idx<6400; idx+=256){
    int n = idx/100, c = idx - n*100;
    float v = (n0+n < N_NODES) ? ldf(x,(long)(n0+n)*100+c,f32m) : 0.f;
    xs[c][n] = v;
  }
  __syncthreads();

  const int ng = t&15, og = t>>4;    // nodes ng*4..+3, outs og*5..+4
  float acc[4][5];
  #pragma unroll
  for(int j=0;j<5;j++){
    float bj = ldf(b, og*5+j, f32m);
    #pragma unroll
    for(int i=0;i<4;i++) acc[i][j] = bj;
  }
  #pragma unroll 2
  for(int c=0;c<100;c++){
    float xv[4];
    #pragma unroll
    for(int i=0;i<4;i++) xv[i] = xs[c][ng*4+i];
    #pragma unroll
    for(int j=0;j<5;j++){
      float wj = Ws[c*80+og*5+j];
      #pragma unroll
      for(int i=0;i<4;i++) acc[i][j] = fmaf(xv[i], wj, acc[i][j]);
    }
  }
  #pragma unroll
  for(int i=0;i<4;i++){
    int n = n0 + ng*4 + i;
    if(n < N_NODES){
      #pragma unroll
      for(int j=0;j<5;j++) h[(long)n*80 + og*5+j] = fmaxf(acc[i][j], 0.f);
    }
  }
}

// ---------------- fused SAGE layer: f32 gather + MFMA matvec ----------------
// block = 4 waves x 16 nodes. Phase 1 (per wave): for each of its 16 nodes,
// float4-gather (4-deep ILP) + reduce -> agg quads; write A-row
// [agg bf16 | h bf16] (K = KT*32) into LDS with XOR swizzle byte^=(row&7)<<4.
// Phase 2 (per wave, wave-local LDS deps, no barrier): C[16xCOUT] = A·Wb via
// mfma_f32_16x16x32_bf16 (A: row=lane&15,k=(lane>>4)*8+j; B frag preloaded
// per-lane; C: col=lane&15,row=(lane>>4)*4+reg). Bias in acc init; L2-norm
// via 16-lane-group shfl_xor; relu; store.

template<int CIN, int COUT, bool LAST>
__global__ __launch_bounds__(256,4) void k_sage(
    const float* __restrict__ hin, const int* __restrict__ off,
    const uint2* __restrict__ csr,
    const short* __restrict__ Wb, const void* __restrict__ bias,
    const int* __restrict__ flags, float* __restrict__ hout, void* __restrict__ outp)
{
  constexpr int KHT  = (CIN+31)/32;          // K-tiles per half: 2 or 3
  constexpr int KT   = 2*KHT;                // 4 or 6
  constexpr int NT   = (COUT+15)/16;         // 4 or 2
  constexpr int ROWB = KT*32*2;              // 256 or 384 bytes per A-row
  constexpr int LPE  = CIN/4;                // 16 or 20
  constexpr int EPW  = 64/LPE;               // 4 or 3

  __shared__ char smem[4*16*ROWB];

  const int f32m = flags[0];
  const int lane = threadIdx.x&63, wid = threadIdx.x>>6;
  const int wnode0 = blockIdx.x*64 + wid*16;
  char* lds = smem + wid*16*ROWB;

  const int sub = lane/LPE;
  const int cl  = lane - sub*LPE;
  const bool lact = (sub < EPW);

  // ---- phase 1: gather + A-row staging ----
  for(int tt=0; tt<16; ++tt){
    const int node = wnode0 + tt;
    if(node >= N_NODES) continue;

    float ax=0.f, ay=0.f, az=0.f, aw=0.f;
    const int e0 = off[node], e1 = off[node+1];
    for(int base=e0; base<e1; base+=64){
      const int cnt = min(64, e1-base);
      uint2 ev = (lane<cnt) ? csr[base+lane] : make_uint2(0u,0u);
      int   sv = (int)ev.x;
      float wv = LAST ? 1.f : __uint_as_float(ev.y);
      for(int j=0; j<cnt; j+=4*EPW){
        int ei0 = j+sub, ei1 = j+EPW+sub, ei2 = j+2*EPW+sub, ei3 = j+3*EPW+sub;
        bool v0 = lact && (ei0<cnt), v1 = lact && (ei1<cnt);
        bool v2 = lact && (ei2<cnt), v3 = lact && (ei3<cnt);
        int x0 = v0?ei0:0, x1 = v1?ei1:0, x2 = v2?ei2:0, x3 = v3?ei3:0;
        int   s0=__shfl(sv,x0), s1=__shfl(sv,x1), s2=__shfl(sv,x2), s3=__shfl(sv,x3);
        float w0=__shfl(wv,x0)*(v0?1.f:0.f), w1=__shfl(wv,x1)*(v1?1.f:0.f);
        float w2=__shfl(wv,x2)*(v2?1.f:0.f), w3=__shfl(wv,x3)*(v3?1.f:0.f);
        const float4 r0 = *(const float4*)(hin + (long)s0*CIN + 4*cl);
        const float4 r1 = *(const float4*)(hin + (long)s1*CIN + 4*cl);
        const float4 r2 = *(const float4*)(hin + (long)s2*CIN + 4*cl);
        const float4 r3 = *(const float4*)(hin + (long)s3*CIN + 4*cl);
        ax = fmaf(w0,r0.x, fmaf(w1,r1.x, fmaf(w2,r2.x, fmaf(w3,r3.x, ax))));
        ay = fmaf(w0,r0.y, fmaf(w1,r1.y, fmaf(w2,r2.y, fmaf(w3,r3.y, ay))));
        az = fmaf(w0,r0.z, fmaf(w1,r1.z, fmaf(w2,r2.z, fmaf(w3,r3.z, az))));
        aw = fmaf(w0,r0.w, fmaf(w1,r1.w, fmaf(w2,r2.w, fmaf(w3,r3.w, aw))));
      }
    }

    if(EPW == 4){
      ax += __shfl_xor(ax,16); ax += __shfl_xor(ax,32);
      ay += __shfl_xor(ay,16); ay += __shfl_xor(ay,32);
      az += __shfl_xor(az,16); az += __shfl_xor(az,32);
      aw += __shfl_xor(aw,16); aw += __shfl_xor(aw,32);
    } else {
      ax = __shfl(ax,cl) + __shfl(ax,cl+20) + __shfl(ax,cl+40);
      ay = __shfl(ay,cl) + __shfl(ay,cl+20) + __shfl(ay,cl+40);
      az = __shfl(az,cl) + __shfl(az,cl+20) + __shfl(az,cl+40);
      aw = __shfl(aw,cl) + __shfl(aw,cl+20) + __shfl(aw,cl+40);
    }
    const float inv = 1.f/fmaxf((float)(e1-e0), 1.f);

    const int sx = (tt&7)<<4;                       // row XOR swizzle
    if(lane < LPE){                                 // agg: bytes 8*lane..+7
      u32 lo = f2bf_rne(ax*inv) | (f2bf_rne(ay*inv)<<16);
      u32 hi = f2bf_rne(az*inv) | (f2bf_rne(aw*inv)<<16);
      int ob = tt*ROWB + lane*8;
      *(uint2*)(lds + (ob^sx)) = make_uint2(lo,hi);
    }
    const float* hs = hin + (long)__builtin_amdgcn_readfirstlane(node)*CIN;
    if(lane < CIN/2){                               // h: bytes KHT*64 + 4*lane
      float2 hv = *(const float2*)(hs + 2*lane);
      u32 pk = f2bf_rne(hv.x) | (f2bf_rne(hv.y)<<16);
      int ob = tt*ROWB + KHT*64 + lane*4;
      *(u32*)(lds + (ob^sx)) = pk;
    }
    if(CIN==80){                                    // zero K-padding
      if(lane>=20 && lane<24){
        int ob = tt*ROWB + 160 + (lane-20)*8;
        *(uint2*)(lds + (ob^sx)) = make_uint2(0u,0u);
      }
      if(lane>=40 && lane<48){
        int ob = tt*ROWB + 352 + (lane-40)*4;
        *(u32*)(lds + (ob^sx)) = 0u;
      }
    }
  }

  // ---- phase 2: MFMA matvec (wave-local LDS reads) ----
  f32x4 acc[NT];
  #pragma unroll
  for(int nt=0; nt<NT; ++nt){
    int col = nt*16 + (lane&15);
    float bv = (col<COUT) ? ldf(bias,col,f32m) : 0.f;
    acc[nt] = (f32x4){bv,bv,bv,bv};
  }
  const int arow = lane&15, kgrp = lane>>4;
  #pragma unroll
  for(int kt=0; kt<KT; ++kt){
    int ob = arow*ROWB + kt*64 + kgrp*16;
    short8 a8 = *(const short8*)(lds + (ob ^ ((arow&7)<<4)));
    #pragma unroll
    for(int nt=0; nt<NT; ++nt){
      short8 b8 = *(const short8*)(Wb + ((long)(kt*NT+nt)*64 + lane)*8);
      acc[nt] = __builtin_amdgcn_mfma_f32_16x16x32_bf16(a8, b8, acc[nt], 0,0,0);
    }
  }

  // ---- epilogue: L2-norm per row, relu, store ----
  float sq[4];
  #pragma unroll
  for(int r=0;r<4;r++){
    float s = 0.f;
    #pragma unroll
    for(int nt=0;nt<NT;nt++){ float v = acc[nt][r]; s = fmaf(v,v,s); }
    #pragma unroll
    for(int d=1; d<16; d<<=1) s += __shfl_xor(s, d);
    sq[r] = s;
  }
  #pragma unroll
  for(int r=0;r<4;r++){
    float rn = 1.f/fmaxf(sqrtf(sq[r]), 1e-12f);
    const int node = wnode0 + 4*(lane>>4) + r;
    #pragma unroll
    for(int nt=0;nt<NT;nt++){
      int col = nt*16 + (lane&15);
      float v = acc[nt][r]*rn;
      if(!LAST) v = fmaxf(v,0.f);
      if(node < N_NODES && col < COUT){
        if(LAST){
          long oi = (long)node*COUT + col;
          if(f32m) ((float*)outp)[oi] = v;
          else     ((bf16*)outp)[oi]  = __float2bfloat16(v);
        } else {
          hout[(long)node*64 + col] = v;
        }
      }
    }
  }
}

// ---------------- launch ----------------

extern "C" void kernel_launch(void* const* d_in, const int* in_sizes, int n_in,
                              void* d_out, int out_size, void* d_ws, size_t ws_size,
                              hipStream_t stream){
  const void* x    = d_in[0];
  const int*  ei   = (const int*)d_in[1];
  const void* ew   = d_in[2];
  const void* embW = d_in[3];
  const void* embB = d_in[4];
  const void *Wl0=d_in[5],  *Wr0=d_in[6],  *b0=d_in[7];
  const void *Wl1=d_in[8],  *Wr1=d_in[9],  *b1=d_in[10];
  const void *Wl2=d_in[11], *Wr2=d_in[12], *b2=d_in[13];
  const void *Wl3=d_in[14], *Wr3=d_in[15], *b3=d_in[16];
  const void *Wlo=d_in[17], *Wro=d_in[18], *bo=d_in[19];

  // 256B-aligned workspace carves (float4/short8 targets must be 16B-aligned)
  char* w = (char*)d_ws;
  auto carve = [&](size_t nbytes)->char*{
    char* r = w; w += (nbytes + 255) & ~(size_t)255; return r;
  };
  int*   flags   = (int*)carve(16);
  int*   deg     = (int*)carve((size_t)N_NODES*4);
  int*   cur     = (int*)carve((size_t)N_NODES*4);
  int*   off     = (int*)carve((size_t)(N_NODES+1)*4);
  int*   bsum    = (int*)carve((size_t)SCAN_BLOCKS*4);
  int*   bbase   = (int*)carve((size_t)SCAN_BLOCKS*4);
  uint2* csr     = (uint2*)carve((size_t)N_EDGES*8);
  short* Wb0     = (short*)carve((size_t)6*4*512*2);
  short* Wb1     = (short*)carve((size_t)4*4*512*2);
  short* Wb2     = (short*)carve((size_t)4*4*512*2);
  short* Wb3     = (short*)carve((size_t)4*4*512*2);
  short* Wbo     = (short*)carve((size_t)4*2*512*2);
  float* hA      = (float*)carve((size_t)N_NODES*80*4);  // stride 80 (layer0 in), reused stride 64 later
  float* hB      = (float*)carve((size_t)N_NODES*64*4);  // stride 64

  k_detect<<<1, 256, 0, stream>>>((const u32*)x, ei, flags);
  k_zero2<<<(N_NODES+255)/256, 256, 0, stream>>>(deg, cur);
  k_count<<<N_EDGES/256, 256, 0, stream>>>(ei, flags, deg);
  k_scan1<<<SCAN_BLOCKS, 256, 0, stream>>>(deg, off, bsum);
  k_scan2<<<1, 512, 0, stream>>>(bsum, bbase);
  k_scan3<<<SCAN_BLOCKS, 256, 0, stream>>>(off, bbase);
  k_fill <<<N_EDGES/256, 256, 0, stream>>>(ei, ew, flags, off, cur, csr);

  k_packb<<<48, 256, 0, stream>>>(Wl0, Wr0, flags, 80, 64, 6, 4, Wb0);
  k_packb<<<32, 256, 0, stream>>>(Wl1, Wr1, flags, 64, 64, 4, 4, Wb1);
  k_packb<<<32, 256, 0, stream>>>(Wl2, Wr2, flags, 64, 64, 4, 4, Wb2);
  k_packb<<<32, 256, 0, stream>>>(Wl3, Wr3, flags, 64, 64, 4, 4, Wb3);
  k_packb<<<16, 256, 0, stream>>>(Wlo, Wro, flags, 64, 18, 4, 2, Wbo);

  k_embed<<<(N_NODES+63)/64, 256, 0, stream>>>(x, embW, embB, flags, hA);

  const int NBLK = (N_NODES+63)/64;   // 1563
  k_sage<80,64,false><<<NBLK, 256, 0, stream>>>(hA, off, csr, Wb0, b0, flags, hB, nullptr);
  k_sage<64,64,false><<<NBLK, 256, 0, stream>>>(hB, off, csr, Wb1, b1, flags, hA, nullptr);
  k_sage<64,64,false><<<NBLK, 256, 0, stream>>>(hA, off, csr, Wb2, b2, flags, hB, nullptr);
  k_sage<64,64,false><<<NBLK, 256, 0, stream>>>(hB, off, csr, Wb3, b3, flags, hA, nullptr);
  k_sage<64,18,true ><<<NBLK, 256, 0, stream>>>(hA, off, csr, Wbo, bo, flags, nullptr, d_out);
}

// Round 16
// 570.901 us; speedup vs baseline: 2.6321x; 1.1407x over previous
//
#include <hip/hip_runtime.h>
#include <hip/hip_bf16.h>

#define N_NODES 100000
#define N_EDGES 1600000
#define SCAN_BLOCKS ((N_NODES+255)/256)   // 391

using bf16 = __hip_bfloat16;
typedef unsigned int u32;
typedef __attribute__((ext_vector_type(8))) short short8;
typedef __attribute__((ext_vector_type(4))) float f32x4;

static __device__ __forceinline__ float b2f(bf16 v){ return __bfloat162float(v); }

// float loader: f32m=1 -> buffer is float32, f32m=0 -> buffer is bf16
static __device__ __forceinline__ float ldf(const void* p, long i, int f32m){
  return f32m ? ((const float*)p)[i] : b2f(((const bf16*)p)[i]);
}

static __device__ __forceinline__ u32 f2bf_rne(float f){
  u32 b = __float_as_uint(f);
  return (b + 0x7fffu + ((b>>16)&1u)) >> 16;
}

// ---------------- dtype detection (device-side, deterministic) ----------------
__global__ void k_detect(const u32* __restrict__ xw, const int* __restrict__ eiw,
                         int* __restrict__ flags){
  __shared__ int s_wild, s_nzodd;
  if(threadIdx.x==0){ s_wild=0; s_nzodd=0; }
  __syncthreads();
  int wild=0, nz=0;
  for(int k=threadIdx.x;k<2048;k+=256){
    u32 w  = xw[k];
    u32 lo = w & 0xffffu;
    int e  = (int)((lo>>7)&0xffu);
    if((lo & 0x7fffu)!=0u && (e<90 || e>160)) wild++;
    if(eiw[2*k+1]!=0) nz++;
  }
  atomicAdd(&s_wild, wild);
  atomicAdd(&s_nzodd, nz);
  __syncthreads();
  if(threadIdx.x==0){
    flags[0] = (s_wild > 512) ? 1 : 0;   // 1: floats are f32
    flags[1] = (s_nzodd == 0) ? 1 : 0;   // 1: indices are int64
  }
}

__global__ void k_zero2(int* __restrict__ a, int* __restrict__ b){
  int i = blockIdx.x*256 + threadIdx.x;
  if(i<N_NODES){ a[i]=0; b[i]=0; }
}

// convert emb weights to f32 workspace (removes per-load dtype branch)
__global__ void k_cvt(const void* __restrict__ W, const void* __restrict__ b,
                      const int* __restrict__ flags, float* __restrict__ Wo,
                      float* __restrict__ bo_){
  int i = blockIdx.x*256 + threadIdx.x;
  int f32m = flags[0];
  if(i<8000) Wo[i] = ldf(W,i,f32m);
  if(i<80)   bo_[i] = ldf(b,i,f32m);
}

// ---------------- CSR build ----------------

__global__ void k_count(const int* __restrict__ ei, const int* __restrict__ flags,
                        int* __restrict__ deg){
  int e = blockIdx.x*256 + threadIdx.x;
  int i64 = flags[1];
  if(e < N_EDGES){
    long di = i64 ? 2l*(N_EDGES + e) : (long)(N_EDGES + e);
    atomicAdd(&deg[ei[di]], 1);
  }
}

// hierarchical exclusive scan of deg[0..N) -> off, block totals -> bsum
__global__ void k_scan1(const int* __restrict__ deg, int* __restrict__ off,
                        int* __restrict__ bsum){
  const int t = threadIdx.x, lane = t&63, wid = t>>6;
  const int i = blockIdx.x*256 + t;
  int v = (i<N_NODES) ? deg[i] : 0;
  const int orig = v;
  #pragma unroll
  for(int d=1; d<64; d<<=1){ int u = __shfl_up(v,d); if(lane>=d) v += u; }
  __shared__ int wsum[4];
  if(lane==63) wsum[wid] = v;
  __syncthreads();
  int wbase = 0;
  for(int k=0;k<wid;k++) wbase += wsum[k];
  if(i<N_NODES) off[i] = wbase + v - orig;          // block-local exclusive
  if(t==255) bsum[blockIdx.x] = wbase + v;          // block total
}

__global__ void k_scan2(const int* __restrict__ bsum, int* __restrict__ bbase){
  const int t = threadIdx.x, lane = t&63, wid = t>>6; // 512 threads, 8 waves
  int v = (t<SCAN_BLOCKS) ? bsum[t] : 0;
  const int orig = v;
  #pragma unroll
  for(int d=1; d<64; d<<=1){ int u = __shfl_up(v,d); if(lane>=d) v += u; }
  __shared__ int wsum[8];
  if(lane==63) wsum[wid] = v;
  __syncthreads();
  int wbase = 0;
  for(int k=0;k<wid;k++) wbase += wsum[k];
  if(t<SCAN_BLOCKS) bbase[t] = wbase + v - orig;    // exclusive block base
}

__global__ void k_scan3(int* __restrict__ off, const int* __restrict__ bbase){
  const int i = blockIdx.x*256 + threadIdx.x;
  if(i<N_NODES) off[i] += bbase[blockIdx.x];
  if(i==0) off[N_NODES] = N_EDGES;
}

// XCD-partitioned CSR fill: block b (XCD b&7 under round-robin) scans edge
// chunk b>>3 and writes only dst in its 12500-node range -> XCD-local,
// single-writer lines (kills write-allocate amplification). Correct for any
// block->XCD mapping; locality is the only thing that varies.
__global__ void k_fill(const int* __restrict__ ei, const void* __restrict__ ew,
                       const int* __restrict__ flags, const int* __restrict__ off,
                       int* __restrict__ cur, uint2* __restrict__ csr){
  const int xcd = blockIdx.x & 7;
  const int e = (blockIdx.x>>3)*256 + threadIdx.x;
  const int i64 = flags[1], f32m = flags[0];
  if(e < N_EDGES){
    int d = ei[i64 ? 2l*(N_EDGES+e) : (long)(N_EDGES+e)];
    if(d/12500 == xcd){
      int s = ei[i64 ? 2l*e : (long)e];
      int p = atomicAdd(&cur[d], 1);
      csr[off[d]+p] = make_uint2((u32)s, __float_as_uint(ldf(ew, e, f32m)));
    }
  }
}

// ---------------- B-fragment pre-pack for MFMA ----------------
// Wfull[K x COUT]: rows 0..khalf-1 = Wl (agg, zero-padded past CIN),
// rows khalf.. = Wr (h). Fragment: out[((kt*NT+nt)*64 + l)*8 + j] =
// Wfull[kt*32 + (l>>4)*8 + j][nt*16 + (l&15)]  (bf16, zero outside).

__global__ void k_packb(const void* __restrict__ Wl, const void* __restrict__ Wr,
                        const int* __restrict__ flags, int CIN, int COUT,
                        int KT, int NT, short* __restrict__ out){
  int idx = blockIdx.x*256 + threadIdx.x;
  int total = KT*NT*512;
  if(idx < total){
    int jj = idx & 7;
    int l  = (idx>>3) & 63;
    int tile = idx >> 9;             // kt*NT + nt
    int nt = tile % NT, kt = tile / NT;
    int k   = kt*32 + ((l>>4)<<3) + jj;
    int col = nt*16 + (l&15);
    int khalf = (KT/2)*32;
    float v = 0.f;
    if(col < COUT){
      int f32m = flags[0];
      if(k < khalf){ if(k < CIN) v = ldf(Wl,(long)k*COUT+col,f32m); }
      else { int ch = k - khalf; if(ch < CIN) v = ldf(Wr,(long)ch*COUT+col,f32m); }
    }
    out[idx] = (short)f2bf_rne(v);
  }
}

// ---------------- embedding: LDS x-tile + global W (L1), 4x5 reg tile ----------------

__global__ __launch_bounds__(256) void k_embed(const void* __restrict__ x,
                                               const float* __restrict__ W,
                                               const float* __restrict__ b,
                                               const int* __restrict__ flags,
                                               float* __restrict__ h){
  __shared__ float xs[100][65];     // [channel][node], pad 65
  const int t = threadIdx.x;
  const int n0 = blockIdx.x*64;
  if(flags[0]){                     // f32 x: float4 staging
    const float* xf = (const float*)x;
    for(int idx=t; idx<1600; idx+=256){
      int n = idx/25, q = idx-25*(idx/25);
      float4 v = (n0+n < N_NODES) ? *(const float4*)(xf + (long)(n0+n)*100 + 4*q)
                                  : make_float4(0.f,0.f,0.f,0.f);
      xs[4*q+0][n]=v.x; xs[4*q+1][n]=v.y; xs[4*q+2][n]=v.z; xs[4*q+3][n]=v.w;
    }
  } else {                          // bf16 x: uint staging (2 ch per u32)
    const u32* xu = (const u32*)x;
    for(int idx=t; idx<3200; idx+=256){
      int n = idx/50, q = idx-50*(idx/50);
      u32 v = (n0+n < N_NODES) ? xu[(long)(n0+n)*50 + q] : 0u;
      xs[2*q+0][n]=__uint_as_float(v<<16);
      xs[2*q+1][n]=__uint_as_float(v&0xffff0000u);
    }
  }
  __syncthreads();

  const int ng = t&15, og = t>>4;    // nodes ng*4..+3, outs og*5..+4
  float acc[4][5];
  #pragma unroll
  for(int j=0;j<5;j++){
    float bj = b[og*5+j];
    #pragma unroll
    for(int i=0;i<4;i++) acc[i][j] = bj;
  }
  #pragma unroll 2
  for(int c=0;c<100;c++){
    float xv[4];
    #pragma unroll
    for(int i=0;i<4;i++) xv[i] = xs[c][ng*4+i];
    #pragma unroll
    for(int j=0;j<5;j++){
      float wj = W[c*80+og*5+j];     // L1-resident, uniform per og-group
      #pragma unroll
      for(int i=0;i<4;i++) acc[i][j] = fmaf(xv[i], wj, acc[i][j]);
    }
  }
  #pragma unroll
  for(int i=0;i<4;i++){
    int n = n0 + ng*4 + i;
    if(n < N_NODES){
      #pragma unroll
      for(int j=0;j<5;j++) h[(long)n*80 + og*5+j] = fmaxf(acc[i][j], 0.f);
    }
  }
}

// ---------------- fused SAGE layer: f32 gather + MFMA matvec ----------------
// block = 2 waves x 16 nodes (grid 3125 = exact). Phase 1 (per wave): gather
// each node (float4, 4-deep ILP), reduce, write A-row [agg|h] bf16 to LDS
// (XOR swizzle). Phase 2 (wave-local): C[16xCOUT] = A·Wb via
// mfma_f32_16x16x32_bf16; bias in acc init; L2-norm via 16-group shfl_xor;
// relu; store.

template<int CIN, int COUT, bool LAST>
__global__ __launch_bounds__(128,6) void k_sage(
    const float* __restrict__ hin, const int* __restrict__ off,
    const uint2* __restrict__ csr,
    const short* __restrict__ Wb, const void* __restrict__ bias,
    const int* __restrict__ flags, float* __restrict__ hout, void* __restrict__ outp)
{
  constexpr int KHT  = (CIN+31)/32;          // K-tiles per half: 2 or 3
  constexpr int KT   = 2*KHT;                // 4 or 6
  constexpr int NT   = (COUT+15)/16;         // 4 or 2
  constexpr int ROWB = KT*32*2;              // 256 or 384 bytes per A-row
  constexpr int LPE  = CIN/4;                // 16 or 20
  constexpr int EPW  = 64/LPE;               // 4 or 3

  __shared__ char smem[2*16*ROWB];

  const int f32m = flags[0];
  const int lane = threadIdx.x&63, wid = threadIdx.x>>6;
  const int wnode0 = blockIdx.x*32 + wid*16;
  char* lds = smem + wid*16*ROWB;

  const int sub = lane/LPE;
  const int cl  = lane - sub*LPE;
  const bool lact = (sub < EPW);

  // ---- phase 1: gather + A-row staging ----
  for(int tt=0; tt<16; ++tt){
    const int node = wnode0 + tt;
    if(node >= N_NODES) continue;

    float ax=0.f, ay=0.f, az=0.f, aw=0.f;
    const int e0 = off[node], e1 = off[node+1];
    for(int base=e0; base<e1; base+=64){
      const int cnt = min(64, e1-base);
      uint2 ev = (lane<cnt) ? csr[base+lane] : make_uint2(0u,0u);
      int   sv = (int)ev.x;
      float wv = LAST ? 1.f : __uint_as_float(ev.y);
      for(int j=0; j<cnt; j+=4*EPW){
        int ei0 = j+sub, ei1 = j+EPW+sub, ei2 = j+2*EPW+sub, ei3 = j+3*EPW+sub;
        bool v0 = lact && (ei0<cnt), v1 = lact && (ei1<cnt);
        bool v2 = lact && (ei2<cnt), v3 = lact && (ei3<cnt);
        int x0 = v0?ei0:0, x1 = v1?ei1:0, x2 = v2?ei2:0, x3 = v3?ei3:0;
        int   s0=__shfl(sv,x0), s1=__shfl(sv,x1), s2=__shfl(sv,x2), s3=__shfl(sv,x3);
        float w0=__shfl(wv,x0)*(v0?1.f:0.f), w1=__shfl(wv,x1)*(v1?1.f:0.f);
        float w2=__shfl(wv,x2)*(v2?1.f:0.f), w3=__shfl(wv,x3)*(v3?1.f:0.f);
        const float4 r0 = *(const float4*)(hin + (long)s0*CIN + 4*cl);
        const float4 r1 = *(const float4*)(hin + (long)s1*CIN + 4*cl);
        const float4 r2 = *(const float4*)(hin + (long)s2*CIN + 4*cl);
        const float4 r3 = *(const float4*)(hin + (long)s3*CIN + 4*cl);
        ax = fmaf(w0,r0.x, fmaf(w1,r1.x, fmaf(w2,r2.x, fmaf(w3,r3.x, ax))));
        ay = fmaf(w0,r0.y, fmaf(w1,r1.y, fmaf(w2,r2.y, fmaf(w3,r3.y, ay))));
        az = fmaf(w0,r0.z, fmaf(w1,r1.z, fmaf(w2,r2.z, fmaf(w3,r3.z, az))));
        aw = fmaf(w0,r0.w, fmaf(w1,r1.w, fmaf(w2,r2.w, fmaf(w3,r3.w, aw))));
      }
    }

    if(EPW == 4){
      ax += __shfl_xor(ax,16); ax += __shfl_xor(ax,32);
      ay += __shfl_xor(ay,16); ay += __shfl_xor(ay,32);
      az += __shfl_xor(az,16); az += __shfl_xor(az,32);
      aw += __shfl_xor(aw,16); aw += __shfl_xor(aw,32);
    } else {
      ax = __shfl(ax,cl) + __shfl(ax,cl+20) + __shfl(ax,cl+40);
      ay = __shfl(ay,cl) + __shfl(ay,cl+20) + __shfl(ay,cl+40);
      az = __shfl(az,cl) + __shfl(az,cl+20) + __shfl(az,cl+40);
      aw = __shfl(aw,cl) + __shfl(aw,cl+20) + __shfl(aw,cl+40);
    }
    const float inv = 1.f/fmaxf((float)(e1-e0), 1.f);

    const int sx = (tt&7)<<4;                       // row XOR swizzle
    if(lane < LPE){                                 // agg: bytes 8*lane..+7
      u32 lo = f2bf_rne(ax*inv) | (f2bf_rne(ay*inv)<<16);
      u32 hi = f2bf_rne(az*inv) | (f2bf_rne(aw*inv)<<16);
      int ob = tt*ROWB + lane*8;
      *(uint2*)(lds + (ob^sx)) = make_uint2(lo,hi);
    }
    const float* hs = hin + (long)__builtin_amdgcn_readfirstlane(node)*CIN;
    if(lane < CIN/2){                               // h: bytes KHT*64 + 4*lane
      float2 hv = *(const float2*)(hs + 2*lane);
      u32 pk = f2bf_rne(hv.x) | (f2bf_rne(hv.y)<<16);
      int ob = tt*ROWB + KHT*64 + lane*4;
      *(u32*)(lds + (ob^sx)) = pk;
    }
    if(CIN==80){                                    // zero K-padding
      if(lane>=20 && lane<24){
        int ob = tt*ROWB + 160 + (lane-20)*8;
        *(uint2*)(lds + (ob^sx)) = make_uint2(0u,0u);
      }
      if(lane>=40 && lane<48){
        int ob = tt*ROWB + 352 + (lane-40)*4;
        *(u32*)(lds + (ob^sx)) = 0u;
      }
    }
  }

  // ---- phase 2: MFMA matvec (wave-local LDS reads) ----
  f32x4 acc[NT];
  #pragma unroll
  for(int nt=0; nt<NT; ++nt){
    int col = nt*16 + (lane&15);
    float bv = (col<COUT) ? ldf(bias,col,f32m) : 0.f;
    acc[nt] = (f32x4){bv,bv,bv,bv};
  }
  const int arow = lane&15, kgrp = lane>>4;
  #pragma unroll
  for(int kt=0; kt<KT; ++kt){
    int ob = arow*ROWB + kt*64 + kgrp*16;
    short8 a8 = *(const short8*)(lds + (ob ^ ((arow&7)<<4)));
    #pragma unroll
    for(int nt=0; nt<NT; ++nt){
      short8 b8 = *(const short8*)(Wb + ((long)(kt*NT+nt)*64 + lane)*8);
      acc[nt] = __builtin_amdgcn_mfma_f32_16x16x32_bf16(a8, b8, acc[nt], 0,0,0);
    }
  }

  // ---- epilogue: L2-norm per row, relu, store ----
  float sq[4];
  #pragma unroll
  for(int r=0;r<4;r++){
    float s = 0.f;
    #pragma unroll
    for(int nt=0;nt<NT;nt++){ float v = acc[nt][r]; s = fmaf(v,v,s); }
    #pragma unroll
    for(int d=1; d<16; d<<=1) s += __shfl_xor(s, d);
    sq[r] = s;
  }
  #pragma unroll
  for(int r=0;r<4;r++){
    float rn = 1.f/fmaxf(sqrtf(sq[r]), 1e-12f);
    const int node = wnode0 + 4*(lane>>4) + r;
    #pragma unroll
    for(int nt=0;nt<NT;nt++){
      int col = nt*16 + (lane&15);
      float v = acc[nt][r]*rn;
      if(!LAST) v = fmaxf(v,0.f);
      if(node < N_NODES && col < COUT){
        if(LAST){
          long oi = (long)node*COUT + col;
          if(f32m) ((float*)outp)[oi] = v;
          else     ((bf16*)outp)[oi]  = __float2bfloat16(v);
        } else {
          hout[(long)node*64 + col] = v;
        }
      }
    }
  }
}

// ---------------- launch ----------------

extern "C" void kernel_launch(void* const* d_in, const int* in_sizes, int n_in,
                              void* d_out, int out_size, void* d_ws, size_t ws_size,
                              hipStream_t stream){
  const void* x    = d_in[0];
  const int*  ei   = (const int*)d_in[1];
  const void* ew   = d_in[2];
  const void* embW = d_in[3];
  const void* embB = d_in[4];
  const void *Wl0=d_in[5],  *Wr0=d_in[6],  *b0=d_in[7];
  const void *Wl1=d_in[8],  *Wr1=d_in[9],  *b1=d_in[10];
  const void *Wl2=d_in[11], *Wr2=d_in[12], *b2=d_in[13];
  const void *Wl3=d_in[14], *Wr3=d_in[15], *b3=d_in[16];
  const void *Wlo=d_in[17], *Wro=d_in[18], *bo=d_in[19];

  // 256B-aligned workspace carves (float4/short8 targets must be 16B-aligned)
  char* w = (char*)d_ws;
  auto carve = [&](size_t nbytes)->char*{
    char* r = w; w += (nbytes + 255) & ~(size_t)255; return r;
  };
  int*   flags   = (int*)carve(16);
  int*   deg     = (int*)carve((size_t)N_NODES*4);
  int*   cur     = (int*)carve((size_t)N_NODES*4);
  int*   off     = (int*)carve((size_t)(N_NODES+1)*4);
  int*   bsum    = (int*)carve((size_t)SCAN_BLOCKS*4);
  int*   bbase   = (int*)carve((size_t)SCAN_BLOCKS*4);
  uint2* csr     = (uint2*)carve((size_t)N_EDGES*8);
  short* Wb0     = (short*)carve((size_t)6*4*512*2);
  short* Wb1     = (short*)carve((size_t)4*4*512*2);
  short* Wb2     = (short*)carve((size_t)4*4*512*2);
  short* Wb3     = (short*)carve((size_t)4*4*512*2);
  short* Wbo     = (short*)carve((size_t)4*2*512*2);
  float* Wef     = (float*)carve((size_t)8000*4);
  float* bef     = (float*)carve((size_t)80*4);
  float* hA      = (float*)carve((size_t)N_NODES*80*4);  // stride 80 (layer0 in), reused stride 64 later
  float* hB      = (float*)carve((size_t)N_NODES*64*4);  // stride 64

  k_detect<<<1, 256, 0, stream>>>((const u32*)x, ei, flags);
  k_zero2<<<(N_NODES+255)/256, 256, 0, stream>>>(deg, cur);
  k_count<<<N_EDGES/256, 256, 0, stream>>>(ei, flags, deg);
  k_scan1<<<SCAN_BLOCKS, 256, 0, stream>>>(deg, off, bsum);
  k_scan2<<<1, 512, 0, stream>>>(bsum, bbase);
  k_scan3<<<SCAN_BLOCKS, 256, 0, stream>>>(off, bbase);
  k_fill <<<8*(N_EDGES/256), 256, 0, stream>>>(ei, ew, flags, off, cur, csr);

  k_cvt  <<<32, 256, 0, stream>>>(embW, embB, flags, Wef, bef);
  k_packb<<<48, 256, 0, stream>>>(Wl0, Wr0, flags, 80, 64, 6, 4, Wb0);
  k_packb<<<32, 256, 0, stream>>>(Wl1, Wr1, flags, 64, 64, 4, 4, Wb1);
  k_packb<<<32, 256, 0, stream>>>(Wl2, Wr2, flags, 64, 64, 4, 4, Wb2);
  k_packb<<<32, 256, 0, stream>>>(Wl3, Wr3, flags, 64, 64, 4, 4, Wb3);
  k_packb<<<16, 256, 0, stream>>>(Wlo, Wro, flags, 64, 18, 4, 2, Wbo);

  k_embed<<<(N_NODES+63)/64, 256, 0, stream>>>(x, Wef, bef, flags, hA);

  const int NBLK = (N_NODES+31)/32;   // 3125 exact
  k_sage<80,64,false><<<NBLK, 128, 0, stream>>>(hA, off, csr, Wb0, b0, flags, hB, nullptr);
  k_sage<64,64,false><<<NBLK, 128, 0, stream>>>(hB, off, csr, Wb1, b1, flags, hA, nullptr);
  k_sage<64,64,false><<<NBLK, 128, 0, stream>>>(hA, off, csr, Wb2, b2, flags, hB, nullptr);
  k_sage<64,64,false><<<NBLK, 128, 0, stream>>>(hB, off, csr, Wb3, b3, flags, hA, nullptr);
  k_sage<64,18,true ><<<NBLK, 128, 0, stream>>>(hA, off, csr, Wbo, bo, flags, nullptr, d_out);
}

// Round 17
// 525.175 us; speedup vs baseline: 2.8613x; 1.0871x over previous
//
#include <hip/hip_runtime.h>
#include <hip/hip_bf16.h>

#define N_NODES 100000
#define N_EDGES 1600000
#define SCAN_BLOCKS ((N_NODES+255)/256)   // 391

using bf16 = __hip_bfloat16;
typedef unsigned int u32;
typedef __attribute__((ext_vector_type(8))) short short8;
typedef __attribute__((ext_vector_type(4))) float f32x4;

static __device__ __forceinline__ float b2f(bf16 v){ return __bfloat162float(v); }

// float loader: f32m=1 -> buffer is float32, f32m=0 -> buffer is bf16
static __device__ __forceinline__ float ldf(const void* p, long i, int f32m){
  return f32m ? ((const float*)p)[i] : b2f(((const bf16*)p)[i]);
}

static __device__ __forceinline__ u32 f2bf_rne(float f){
  u32 b = __float_as_uint(f);
  return (b + 0x7fffu + ((b>>16)&1u)) >> 16;
}

// ---------------- dtype detection (device-side, deterministic) ----------------
__global__ void k_detect(const u32* __restrict__ xw, const int* __restrict__ eiw,
                         int* __restrict__ flags){
  __shared__ int s_wild, s_nzodd;
  if(threadIdx.x==0){ s_wild=0; s_nzodd=0; }
  __syncthreads();
  int wild=0, nz=0;
  for(int k=threadIdx.x;k<2048;k+=256){
    u32 w  = xw[k];
    u32 lo = w & 0xffffu;
    int e  = (int)((lo>>7)&0xffu);
    if((lo & 0x7fffu)!=0u && (e<90 || e>160)) wild++;
    if(eiw[2*k+1]!=0) nz++;
  }
  atomicAdd(&s_wild, wild);
  atomicAdd(&s_nzodd, nz);
  __syncthreads();
  if(threadIdx.x==0){
    flags[0] = (s_wild > 512) ? 1 : 0;   // 1: floats are f32
    flags[1] = (s_nzodd == 0) ? 1 : 0;   // 1: indices are int64
  }
}

__global__ void k_zero2(int* __restrict__ a, int* __restrict__ b){
  int i = blockIdx.x*256 + threadIdx.x;
  if(i<N_NODES){ a[i]=0; b[i]=0; }
}

// convert emb weights to f32 workspace (removes per-load dtype branch)
__global__ void k_cvt(const void* __restrict__ W, const void* __restrict__ b,
                      const int* __restrict__ flags, float* __restrict__ Wo,
                      float* __restrict__ bo_){
  int i = blockIdx.x*256 + threadIdx.x;
  int f32m = flags[0];
  if(i<8000) Wo[i] = ldf(W,i,f32m);
  if(i<80)   bo_[i] = ldf(b,i,f32m);
}

// ---------------- CSR build ----------------

__global__ void k_count(const int* __restrict__ ei, const int* __restrict__ flags,
                        int* __restrict__ deg){
  int e = blockIdx.x*256 + threadIdx.x;
  int i64 = flags[1];
  if(e < N_EDGES){
    long di = i64 ? 2l*(N_EDGES + e) : (long)(N_EDGES + e);
    atomicAdd(&deg[ei[di]], 1);
  }
}

// hierarchical exclusive scan of deg[0..N) -> off, block totals -> bsum
__global__ void k_scan1(const int* __restrict__ deg, int* __restrict__ off,
                        int* __restrict__ bsum){
  const int t = threadIdx.x, lane = t&63, wid = t>>6;
  const int i = blockIdx.x*256 + t;
  int v = (i<N_NODES) ? deg[i] : 0;
  const int orig = v;
  #pragma unroll
  for(int d=1; d<64; d<<=1){ int u = __shfl_up(v,d); if(lane>=d) v += u; }
  __shared__ int wsum[4];
  if(lane==63) wsum[wid] = v;
  __syncthreads();
  int wbase = 0;
  for(int k=0;k<wid;k++) wbase += wsum[k];
  if(i<N_NODES) off[i] = wbase + v - orig;          // block-local exclusive
  if(t==255) bsum[blockIdx.x] = wbase + v;          // block total
}

__global__ void k_scan2(const int* __restrict__ bsum, int* __restrict__ bbase){
  const int t = threadIdx.x, lane = t&63, wid = t>>6; // 512 threads, 8 waves
  int v = (t<SCAN_BLOCKS) ? bsum[t] : 0;
  const int orig = v;
  #pragma unroll
  for(int d=1; d<64; d<<=1){ int u = __shfl_up(v,d); if(lane>=d) v += u; }
  __shared__ int wsum[8];
  if(lane==63) wsum[wid] = v;
  __syncthreads();
  int wbase = 0;
  for(int k=0;k<wid;k++) wbase += wsum[k];
  if(t<SCAN_BLOCKS) bbase[t] = wbase + v - orig;    // exclusive block base
}

__global__ void k_scan3(int* __restrict__ off, const int* __restrict__ bbase){
  const int i = blockIdx.x*256 + threadIdx.x;
  if(i<N_NODES) off[i] += bbase[blockIdx.x];
  if(i==0) off[N_NODES] = N_EDGES;
}

// XCD-partitioned CSR fill (round-15 win): block b writes only its dst range.
__global__ void k_fill(const int* __restrict__ ei, const void* __restrict__ ew,
                       const int* __restrict__ flags, const int* __restrict__ off,
                       int* __restrict__ cur, uint2* __restrict__ csr){
  const int xcd = blockIdx.x & 7;
  const int e = (blockIdx.x>>3)*256 + threadIdx.x;
  const int i64 = flags[1], f32m = flags[0];
  if(e < N_EDGES){
    int d = ei[i64 ? 2l*(N_EDGES+e) : (long)(N_EDGES+e)];
    if(d/12500 == xcd){
      int s = ei[i64 ? 2l*e : (long)e];
      int p = atomicAdd(&cur[d], 1);
      csr[off[d]+p] = make_uint2((u32)s, __float_as_uint(ldf(ew, e, f32m)));
    }
  }
}

// ---------------- B-fragment pre-pack for MFMA ----------------

__global__ void k_packb(const void* __restrict__ Wl, const void* __restrict__ Wr,
                        const int* __restrict__ flags, int CIN, int COUT,
                        int KT, int NT, short* __restrict__ out){
  int idx = blockIdx.x*256 + threadIdx.x;
  int total = KT*NT*512;
  if(idx < total){
    int jj = idx & 7;
    int l  = (idx>>3) & 63;
    int tile = idx >> 9;             // kt*NT + nt
    int nt = tile % NT, kt = tile / NT;
    int k   = kt*32 + ((l>>4)<<3) + jj;
    int col = nt*16 + (l&15);
    int khalf = (KT/2)*32;
    float v = 0.f;
    if(col < COUT){
      int f32m = flags[0];
      if(k < khalf){ if(k < CIN) v = ldf(Wl,(long)k*COUT+col,f32m); }
      else { int ch = k - khalf; if(ch < CIN) v = ldf(Wr,(long)ch*COUT+col,f32m); }
    }
    out[idx] = (short)f2bf_rne(v);
  }
}

// ---------------- embedding: LDS x-tile + global W (L1), bf16 output ----------------

__global__ __launch_bounds__(256) void k_embed(const void* __restrict__ x,
                                               const float* __restrict__ W,
                                               const float* __restrict__ b,
                                               const int* __restrict__ flags,
                                               bf16* __restrict__ h){
  __shared__ float xs[100][65];     // [channel][node], pad 65
  const int t = threadIdx.x;
  const int n0 = blockIdx.x*64;
  if(flags[0]){                     // f32 x: float4 staging
    const float* xf = (const float*)x;
    for(int idx=t; idx<1600; idx+=256){
      int n = idx/25, q = idx-25*(idx/25);
      float4 v = (n0+n < N_NODES) ? *(const float4*)(xf + (long)(n0+n)*100 + 4*q)
                                  : make_float4(0.f,0.f,0.f,0.f);
      xs[4*q+0][n]=v.x; xs[4*q+1][n]=v.y; xs[4*q+2][n]=v.z; xs[4*q+3][n]=v.w;
    }
  } else {                          // bf16 x: uint staging (2 ch per u32)
    const u32* xu = (const u32*)x;
    for(int idx=t; idx<3200; idx+=256){
      int n = idx/50, q = idx-50*(idx/50);
      u32 v = (n0+n < N_NODES) ? xu[(long)(n0+n)*50 + q] : 0u;
      xs[2*q+0][n]=__uint_as_float(v<<16);
      xs[2*q+1][n]=__uint_as_float(v&0xffff0000u);
    }
  }
  __syncthreads();

  const int ng = t&15, og = t>>4;    // nodes ng*4..+3, outs og*5..+4
  float acc[4][5];
  #pragma unroll
  for(int j=0;j<5;j++){
    float bj = b[og*5+j];
    #pragma unroll
    for(int i=0;i<4;i++) acc[i][j] = bj;
  }
  #pragma unroll 2
  for(int c=0;c<100;c++){
    float xv[4];
    #pragma unroll
    for(int i=0;i<4;i++) xv[i] = xs[c][ng*4+i];
    #pragma unroll
    for(int j=0;j<5;j++){
      float wj = W[c*80+og*5+j];
      #pragma unroll
      for(int i=0;i<4;i++) acc[i][j] = fmaf(xv[i], wj, acc[i][j]);
    }
  }
  #pragma unroll
  for(int i=0;i<4;i++){
    int n = n0 + ng*4 + i;
    if(n < N_NODES){
      #pragma unroll
      for(int j=0;j<5;j++)
        h[(long)n*80 + og*5+j] = __float2bfloat16(fmaxf(acc[i][j], 0.f));
    }
  }
}

// ---------------- fused SAGE layer: bf16-row gather + MFMA matvec ----------------
// h rows are bf16, RB=CIN*2 bytes. Gather: LPE=CIN/8 lanes per edge read uint4
// (8 ch each); EPW=64/LPE edges per wave-load, 4-deep ILP. Unpack-fma into
// f32 a[8]. Reduce across edge groups (xor for LPE=8; 6-term bpermute for
// LPE=10). A-row staging: one uint4 LDS write/lane (agg, bf16-packed) + raw
// uint4 copy of self row. MFMA C=A·Wb; bias init; 16-group L2-norm; relu;
// bf16 store.

template<int CIN, int COUT, bool LAST>
__global__ __launch_bounds__(128,6) void k_sage(
    const void* __restrict__ hin, const int* __restrict__ off,
    const uint2* __restrict__ csr,
    const short* __restrict__ Wb, const void* __restrict__ bias,
    const int* __restrict__ flags, bf16* __restrict__ hout, void* __restrict__ outp)
{
  constexpr int RB   = CIN*2;                // bf16 row bytes: 128 or 160
  constexpr int KHT  = (CIN+31)/32;          // K-tiles per half: 2 or 3
  constexpr int KT   = 2*KHT;                // 4 or 6
  constexpr int NT   = (COUT+15)/16;         // 4 or 2
  constexpr int ROWB = KT*32*2;              // 256 or 384 bytes per A-row
  constexpr int LPE  = CIN/8;                // lanes per edge-row: 8 or 10
  constexpr int EPW  = 64/LPE;               // edges per wave load: 8 or 6

  __shared__ char smem[2*16*ROWB];

  const int f32m = flags[0];
  const int lane = threadIdx.x&63, wid = threadIdx.x>>6;
  const int wnode0 = blockIdx.x*32 + wid*16;
  char* lds = smem + wid*16*ROWB;

  const int sub = lane/LPE;
  const int cl  = lane - sub*LPE;
  const bool lact = (sub < EPW);
  const char* hinb = (const char*)hin;

  // ---- phase 1: gather + A-row staging ----
  for(int tt=0; tt<16; ++tt){
    const int node = wnode0 + tt;
    if(node >= N_NODES) continue;

    float a[8];
    #pragma unroll
    for(int k=0;k<8;k++) a[k]=0.f;

    const int e0 = off[node], e1 = off[node+1];
    for(int base=e0; base<e1; base+=64){
      const int cnt = min(64, e1-base);
      uint2 ev = (lane<cnt) ? csr[base+lane] : make_uint2(0u,0u);
      int   sv = (int)ev.x;
      float wv = LAST ? 1.f : __uint_as_float(ev.y);
      for(int j=0; j<cnt; j+=4*EPW){
        int ei0 = j+sub, ei1 = j+EPW+sub, ei2 = j+2*EPW+sub, ei3 = j+3*EPW+sub;
        bool v0 = lact && (ei0<cnt), v1 = lact && (ei1<cnt);
        bool v2 = lact && (ei2<cnt), v3 = lact && (ei3<cnt);
        int x0 = v0?ei0:0, x1 = v1?ei1:0, x2 = v2?ei2:0, x3 = v3?ei3:0;
        int   s0=__shfl(sv,x0), s1=__shfl(sv,x1), s2=__shfl(sv,x2), s3=__shfl(sv,x3);
        float w0=__shfl(wv,x0)*(v0?1.f:0.f), w1=__shfl(wv,x1)*(v1?1.f:0.f);
        float w2=__shfl(wv,x2)*(v2?1.f:0.f), w3=__shfl(wv,x3)*(v3?1.f:0.f);
        uint4 r0 = *(const uint4*)(hinb + (long)s0*RB + 16*cl);
        uint4 r1 = *(const uint4*)(hinb + (long)s1*RB + 16*cl);
        uint4 r2 = *(const uint4*)(hinb + (long)s2*RB + 16*cl);
        uint4 r3 = *(const uint4*)(hinb + (long)s3*RB + 16*cl);
        #define ACC8(rr,ww) \
          a[0]=fmaf(ww,__uint_as_float(rr.x<<16),a[0]); \
          a[1]=fmaf(ww,__uint_as_float(rr.x&0xffff0000u),a[1]); \
          a[2]=fmaf(ww,__uint_as_float(rr.y<<16),a[2]); \
          a[3]=fmaf(ww,__uint_as_float(rr.y&0xffff0000u),a[3]); \
          a[4]=fmaf(ww,__uint_as_float(rr.z<<16),a[4]); \
          a[5]=fmaf(ww,__uint_as_float(rr.z&0xffff0000u),a[5]); \
          a[6]=fmaf(ww,__uint_as_float(rr.w<<16),a[6]); \
          a[7]=fmaf(ww,__uint_as_float(rr.w&0xffff0000u),a[7]);
        ACC8(r0,w0); ACC8(r1,w1); ACC8(r2,w2); ACC8(r3,w3);
        #undef ACC8
      }
    }

    // reduce across edge groups -> lane q<LPE holds channels 8q..8q+7
    if(LPE==8){
      #pragma unroll
      for(int k=0;k<8;k++){
        a[k]+=__shfl_xor(a[k],8); a[k]+=__shfl_xor(a[k],16); a[k]+=__shfl_xor(a[k],32);
      }
    } else {
      #pragma unroll
      for(int k=0;k<8;k++){
        a[k] = __shfl(a[k],cl)    + __shfl(a[k],cl+10) + __shfl(a[k],cl+20)
             + __shfl(a[k],cl+30) + __shfl(a[k],cl+40) + __shfl(a[k],cl+50);
      }
    }
    const float inv = 1.f/fmaxf((float)(e1-e0), 1.f);

    const int sx = (tt&7)<<4;                       // row XOR swizzle
    if(lane < LPE){                                 // agg: 16B per lane
      u32 p0 = f2bf_rne(a[0]*inv) | (f2bf_rne(a[1]*inv)<<16);
      u32 p1 = f2bf_rne(a[2]*inv) | (f2bf_rne(a[3]*inv)<<16);
      u32 p2 = f2bf_rne(a[4]*inv) | (f2bf_rne(a[5]*inv)<<16);
      u32 p3 = f2bf_rne(a[6]*inv) | (f2bf_rne(a[7]*inv)<<16);
      int ob = tt*ROWB + lane*16;
      *(uint4*)(lds + (ob^sx)) = make_uint4(p0,p1,p2,p3);
    }
    if(CIN==80 && lane>=10 && lane<12){             // agg K-pad bytes 160..191
      int ob = tt*ROWB + lane*16;
      *(uint4*)(lds + (ob^sx)) = make_uint4(0u,0u,0u,0u);
    }
    const char* hsb = hinb + (long)__builtin_amdgcn_readfirstlane(node)*RB;
    if(lane < RB/16){                               // raw self-row copy
      uint4 hv = *(const uint4*)(hsb + lane*16);
      int ob = tt*ROWB + KHT*64 + lane*16;
      *(uint4*)(lds + (ob^sx)) = hv;
    }
    if(CIN==80 && lane>=20 && lane<22){             // h K-pad bytes 352..383
      int ob = tt*ROWB + KHT*64 + (lane-10)*16;
      *(uint4*)(lds + (ob^sx)) = make_uint4(0u,0u,0u,0u);
    }
  }

  // ---- phase 2: MFMA matvec (wave-local LDS reads) ----
  f32x4 acc[NT];
  #pragma unroll
  for(int nt=0; nt<NT; ++nt){
    int col = nt*16 + (lane&15);
    float bv = (col<COUT) ? ldf(bias,col,f32m) : 0.f;
    acc[nt] = (f32x4){bv,bv,bv,bv};
  }
  const int arow = lane&15, kgrp = lane>>4;
  #pragma unroll
  for(int kt=0; kt<KT; ++kt){
    int ob = arow*ROWB + kt*64 + kgrp*16;
    short8 a8 = *(const short8*)(lds + (ob ^ ((arow&7)<<4)));
    #pragma unroll
    for(int nt=0; nt<NT; ++nt){
      short8 b8 = *(const short8*)(Wb + ((long)(kt*NT+nt)*64 + lane)*8);
      acc[nt] = __builtin_amdgcn_mfma_f32_16x16x32_bf16(a8, b8, acc[nt], 0,0,0);
    }
  }

  // ---- epilogue: L2-norm per row, relu, store ----
  float sq[4];
  #pragma unroll
  for(int r=0;r<4;r++){
    float s = 0.f;
    #pragma unroll
    for(int nt=0;nt<NT;nt++){ float v = acc[nt][r]; s = fmaf(v,v,s); }
    #pragma unroll
    for(int d=1; d<16; d<<=1) s += __shfl_xor(s, d);
    sq[r] = s;
  }
  #pragma unroll
  for(int r=0;r<4;r++){
    float rn = 1.f/fmaxf(sqrtf(sq[r]), 1e-12f);
    const int node = wnode0 + 4*(lane>>4) + r;
    #pragma unroll
    for(int nt=0;nt<NT;nt++){
      int col = nt*16 + (lane&15);
      float v = acc[nt][r]*rn;
      if(!LAST) v = fmaxf(v,0.f);
      if(node < N_NODES && col < COUT){
        if(LAST){
          long oi = (long)node*COUT + col;
          if(f32m) ((float*)outp)[oi] = v;
          else     ((bf16*)outp)[oi]  = __float2bfloat16(v);
        } else {
          hout[(long)node*64 + col] = __float2bfloat16(v);
        }
      }
    }
  }
}

// ---------------- launch ----------------

extern "C" void kernel_launch(void* const* d_in, const int* in_sizes, int n_in,
                              void* d_out, int out_size, void* d_ws, size_t ws_size,
                              hipStream_t stream){
  const void* x    = d_in[0];
  const int*  ei   = (const int*)d_in[1];
  const void* ew   = d_in[2];
  const void* embW = d_in[3];
  const void* embB = d_in[4];
  const void *Wl0=d_in[5],  *Wr0=d_in[6],  *b0=d_in[7];
  const void *Wl1=d_in[8],  *Wr1=d_in[9],  *b1=d_in[10];
  const void *Wl2=d_in[11], *Wr2=d_in[12], *b2=d_in[13];
  const void *Wl3=d_in[14], *Wr3=d_in[15], *b3=d_in[16];
  const void *Wlo=d_in[17], *Wro=d_in[18], *bo=d_in[19];

  // 256B-aligned workspace carves (uint4/short8 targets must be 16B-aligned)
  char* w = (char*)d_ws;
  auto carve = [&](size_t nbytes)->char*{
    char* r = w; w += (nbytes + 255) & ~(size_t)255; return r;
  };
  int*   flags   = (int*)carve(16);
  int*   deg     = (int*)carve((size_t)N_NODES*4);
  int*   cur     = (int*)carve((size_t)N_NODES*4);
  int*   off     = (int*)carve((size_t)(N_NODES+1)*4);
  int*   bsum    = (int*)carve((size_t)SCAN_BLOCKS*4);
  int*   bbase   = (int*)carve((size_t)SCAN_BLOCKS*4);
  uint2* csr     = (uint2*)carve((size_t)N_EDGES*8);
  short* Wb0     = (short*)carve((size_t)6*4*512*2);
  short* Wb1     = (short*)carve((size_t)4*4*512*2);
  short* Wb2     = (short*)carve((size_t)4*4*512*2);
  short* Wb3     = (short*)carve((size_t)4*4*512*2);
  short* Wbo     = (short*)carve((size_t)4*2*512*2);
  float* Wef     = (float*)carve((size_t)8000*4);
  float* bef     = (float*)carve((size_t)80*4);
  bf16*  hE      = (bf16*)carve((size_t)N_NODES*80*2);   // embed out, 160B rows
  bf16*  hA      = (bf16*)carve((size_t)N_NODES*64*2);   // 128B rows
  bf16*  hB      = (bf16*)carve((size_t)N_NODES*64*2);

  k_detect<<<1, 256, 0, stream>>>((const u32*)x, ei, flags);
  k_zero2<<<(N_NODES+255)/256, 256, 0, stream>>>(deg, cur);
  k_count<<<N_EDGES/256, 256, 0, stream>>>(ei, flags, deg);
  k_scan1<<<SCAN_BLOCKS, 256, 0, stream>>>(deg, off, bsum);
  k_scan2<<<1, 512, 0, stream>>>(bsum, bbase);
  k_scan3<<<SCAN_BLOCKS, 256, 0, stream>>>(off, bbase);
  k_fill <<<8*(N_EDGES/256), 256, 0, stream>>>(ei, ew, flags, off, cur, csr);

  k_cvt  <<<32, 256, 0, stream>>>(embW, embB, flags, Wef, bef);
  k_packb<<<48, 256, 0, stream>>>(Wl0, Wr0, flags, 80, 64, 6, 4, Wb0);
  k_packb<<<32, 256, 0, stream>>>(Wl1, Wr1, flags, 64, 64, 4, 4, Wb1);
  k_packb<<<32, 256, 0, stream>>>(Wl2, Wr2, flags, 64, 64, 4, 4, Wb2);
  k_packb<<<32, 256, 0, stream>>>(Wl3, Wr3, flags, 64, 64, 4, 4, Wb3);
  k_packb<<<16, 256, 0, stream>>>(Wlo, Wro, flags, 64, 18, 4, 2, Wbo);

  k_embed<<<(N_NODES+63)/64, 256, 0, stream>>>(x, Wef, bef, flags, hE);

  const int NBLK = (N_NODES+31)/32;   // 3125 exact
  k_sage<80,64,false><<<NBLK, 128, 0, stream>>>(hE, off, csr, Wb0, b0, flags, hA, nullptr);
  k_sage<64,64,false><<<NBLK, 128, 0, stream>>>(hA, off, csr, Wb1, b1, flags, hB, nullptr);
  k_sage<64,64,false><<<NBLK, 128, 0, stream>>>(hB, off, csr, Wb2, b2, flags, hA, nullptr);
  k_sage<64,64,false><<<NBLK, 128, 0, stream>>>(hA, off, csr, Wb3, b3, flags, hB, nullptr);
  k_sage<64,18,true ><<<NBLK, 128, 0, stream>>>(hB, off, csr, Wbo, bo, flags, nullptr, d_out);
}